// Round 3
// baseline (10663.754 us; speedup 1.0000x reference)
//
#include <hip/hip_runtime.h>
#include <math.h>

#define LRELU(v) ((v) >= 0.f ? (v) : 0.2f*(v))

__device__ __forceinline__ float sigmoidf_(float x){ return 1.f/(1.f + expf(-x)); }

// ---------------------------------------------------------------------------
// conv1: x (Nimg,1,128,128) -> e1 (Nimg,16,64,64), k3 s2 p1, bias+lrelu
// ---------------------------------------------------------------------------
__global__ __launch_bounds__(256) void k_conv1(const float* __restrict__ x,
    const float* __restrict__ W, const float* __restrict__ Bb, float* __restrict__ out)
{
    __shared__ float wl[144];
    __shared__ float bl[16];
    int tid = threadIdx.x;
    if (tid < 144) { int oc = tid/9, tap = tid%9; wl[tap*16+oc] = W[oc*9+tap]; }
    if (tid < 16) bl[tid] = Bb[tid];
    __syncthreads();
    int img = blockIdx.y;
    int px = blockIdx.x*256 + tid;
    int oy = px >> 6, ox = px & 63;
    const float* xin = x + (size_t)img*16384;
    float acc[16];
    #pragma unroll
    for (int o=0;o<16;++o) acc[o]=bl[o];
    #pragma unroll
    for (int kh=0; kh<3; ++kh){
        int iy = 2*oy + kh - 1;
        bool vy = (iy>=0 && iy<128);
        #pragma unroll
        for (int kw=0; kw<3; ++kw){
            int ix = 2*ox + kw - 1;
            float v = (vy && ix>=0 && ix<128) ? xin[iy*128+ix] : 0.f;
            int tap = kh*3+kw;
            #pragma unroll
            for (int o=0;o<16;++o) acc[o] += wl[tap*16+o]*v;
        }
    }
    float* op = out + (size_t)img*65536 + px;
    #pragma unroll
    for (int o=0;o<16;++o){ float v = acc[o]; op[o*4096] = LRELU(v); }
}

// ---------------------------------------------------------------------------
// conv2: e1 (Nimg,16,64,64) -> e2 (Nimg,64,32,32), k3 s2 p1, bias+lrelu
// ---------------------------------------------------------------------------
__global__ __launch_bounds__(256) void k_conv2(const float* __restrict__ in,
    const float* __restrict__ W, const float* __restrict__ Bb, float* __restrict__ out)
{
    __shared__ float tile[2*65*68];
    __shared__ float wl[2*9*16];
    int tid = threadIdx.x;
    int img = blockIdx.y;
    int ocBase = blockIdx.x*16;
    int y = tid >> 3, xg = tid & 7, x0 = xg*4;
    float acc[16][4];
    #pragma unroll
    for (int o=0;o<16;++o){ float b = Bb[ocBase+o];
        #pragma unroll
        for (int p=0;p<4;++p) acc[o][p] = b; }
    const float* base = in + (size_t)img*65536;
    for (int icB=0; icB<16; icB+=2){
        for (int e=tid; e<2210; e+=256){            // 2*65*17 float4
            int c4 = e % 17; int rr = (e/17)%65; int ch = e/(17*65);
            int iy = rr - 1; int ixb = c4*4 - 4;
            float4 v = make_float4(0.f,0.f,0.f,0.f);
            if (iy>=0 && iy<64 && c4>=1)
                v = *(const float4*)(base + (icB+ch)*4096 + iy*64 + ixb);
            *(float4*)(&tile[ch*4420 + rr*68 + c4*4]) = v;
        }
        for (int e=tid; e<288; e+=256){
            int oc = e & 15; int rest = e >> 4; int tap = rest % 9; int ch = rest/9;
            wl[(ch*9+tap)*16 + oc] = W[((ocBase+oc)*16 + icB+ch)*9 + tap];
        }
        __syncthreads();
        #pragma unroll
        for (int ch=0; ch<2; ++ch){
            #pragma unroll
            for (int kh=0; kh<3; ++kh){
                int r = 2*y + kh;
                const float4* row = (const float4*)(&tile[ch*4420 + r*68 + 2*x0]);
                float4 a0=row[0], a1=row[1], a2=row[2];
                float win[12] = {a0.x,a0.y,a0.z,a0.w,a1.x,a1.y,a1.z,a1.w,a2.x,a2.y,a2.z,a2.w};
                #pragma unroll
                for (int kw=0; kw<3; ++kw){
                    const float4* wp = (const float4*)(&wl[(ch*9+kh*3+kw)*16]);
                    float4 w0=wp[0], w1=wp[1], w2=wp[2], w3=wp[3];
                    float wv[16] = {w0.x,w0.y,w0.z,w0.w,w1.x,w1.y,w1.z,w1.w,
                                    w2.x,w2.y,w2.z,w2.w,w3.x,w3.y,w3.z,w3.w};
                    #pragma unroll
                    for (int p=0;p<4;++p){
                        float v = win[2*p + kw + 3];
                        #pragma unroll
                        for (int o=0;o<16;++o) acc[o][p] += wv[o]*v;
                    }
                }
            }
        }
        __syncthreads();
    }
    float* op = out + (size_t)img*65536 + (size_t)ocBase*1024 + y*32 + x0;
    #pragma unroll
    for (int o=0;o<16;++o){
        float4 v = make_float4(LRELU(acc[o][0]),LRELU(acc[o][1]),LRELU(acc[o][2]),LRELU(acc[o][3]));
        *(float4*)(op + o*1024) = v;
    }
}

// ---------------------------------------------------------------------------
// conv5: 5x5 pad2 s1 over 32x32, input = concat(inA[icA ch], inB[rest]),
// partial sums over ic-splits into P[split][32][ocTot][1024] (no bias/act).
// grid (ocTot/4, 32, nsplit), block 128. thread: 8 px (row seg) x 4 oc.
// LDS: tile [2][36][44] (13.5 KB total) -> ~11 blocks/CU LDS-wise; grid gives
// 8 blocks/CU = 16 waves/CU (occupancy fix: was 8 waves/CU at 8px x 8oc).
// ---------------------------------------------------------------------------
__global__ __launch_bounds__(128) void k_conv5(
    const float* __restrict__ inA, int icA, int strA,
    const float* __restrict__ inB, int strB,
    const float* __restrict__ W, int wIcTot, int wIcOff,
    int icTotal, int ocTot,
    float* __restrict__ P)
{
    __shared__ float tile[2*36*44];   // 3168 floats
    __shared__ float wl[2*25*4];      // 200 floats
    int tid = threadIdx.x;
    int b = blockIdx.y;
    int ocBase = blockIdx.x*4;
    int split = blockIdx.z, nsplit = gridDim.z;
    int icCount = icTotal / nsplit;
    int icStart = split * icCount;
    int y = tid >> 2, xg = tid & 3, x0 = xg*8;
    float acc[4][8];
    #pragma unroll
    for (int o=0;o<4;++o)
        #pragma unroll
        for (int p=0;p<8;++p) acc[o][p]=0.f;

    for (int cb=0; cb<icCount; cb+=2){
        for (int e=tid; e<792; e+=128){            // 2*36*11 float4
            int c4 = e % 11; int rr = (e/11) % 36; int ch = e/(11*36);
            int j = icStart + cb + ch;
            int iy = rr - 2; int ixb = c4*4 - 4;
            float4 v = make_float4(0.f,0.f,0.f,0.f);
            if (iy>=0 && iy<32 && c4>=1 && c4<=8){
                const float* src = (j < icA) ? (inA + (size_t)b*strA + (size_t)j*1024)
                                             : (inB + (size_t)b*strB + (size_t)(j-icA)*1024);
                v = *(const float4*)(src + iy*32 + ixb);
            }
            *(float4*)(&tile[ch*1584 + rr*44 + c4*4]) = v;
        }
        for (int e=tid; e<200; e+=128){
            int oc = e & 3; int rest = e >> 2; int tap = rest % 25; int ch = rest/25;
            int j = icStart + cb + ch;
            wl[(ch*25+tap)*4 + oc] = W[((size_t)(ocBase+oc)*wIcTot + wIcOff + j)*25 + tap];
        }
        __syncthreads();
        #pragma unroll
        for (int ch=0; ch<2; ++ch){
            #pragma unroll
            for (int kh=0; kh<5; ++kh){
                const float4* row = (const float4*)(&tile[ch*1584 + (y+kh)*44 + x0]);
                float4 a0=row[0], a1=row[1], a2=row[2], a3=row[3];
                float win[16] = {a0.x,a0.y,a0.z,a0.w,a1.x,a1.y,a1.z,a1.w,
                                 a2.x,a2.y,a2.z,a2.w,a3.x,a3.y,a3.z,a3.w};
                #pragma unroll
                for (int kw=0; kw<5; ++kw){
                    const float4* wp = (const float4*)(&wl[(ch*25+kh*5+kw)*4]);
                    float4 wa = wp[0];
                    #pragma unroll
                    for (int p=0;p<8;++p){
                        float v = win[p+kw+2];
                        acc[0][p] += wa.x*v; acc[1][p] += wa.y*v;
                        acc[2][p] += wa.z*v; acc[3][p] += wa.w*v;
                    }
                }
            }
        }
        __syncthreads();
    }
    float* op = P + (((size_t)split*32 + b)*ocTot + ocBase)*1024 + y*32 + x0;
    #pragma unroll
    for (int o=0;o<4;++o){
        *(float4*)(op + o*1024 + 0) = make_float4(acc[o][0],acc[o][1],acc[o][2],acc[o][3]);
        *(float4*)(op + o*1024 + 4) = make_float4(acc[o][4],acc[o][5],acc[o][6],acc[o][7]);
    }
}

// ---------------------------------------------------------------------------
// combine zr: r=sig(P0+P1+b[0:64]), z=sig(..[64:128]); rh=r*h; store z.
// ---------------------------------------------------------------------------
__global__ __launch_bounds__(256) void k_comb_zr(const float* __restrict__ P,
    const float* __restrict__ h, const float* __restrict__ bzr,
    float* __restrict__ rh, float* __restrict__ zout)
{
    int i = blockIdx.x*256 + threadIdx.x;      // over 32*64*256 float4
    int q = i & 255; int c = (i >> 8) & 63; int b = i >> 14;
    const float4* P4 = (const float4*)P;
    size_t ir = (((size_t)b*128) + c)*256 + q;
    size_t iz = (((size_t)b*128) + c + 64)*256 + q;
    size_t s1 = (size_t)32*128*256;
    float4 pr = P4[ir], pr2 = P4[ir + s1];
    float4 pz = P4[iz], pz2 = P4[iz + s1];
    float br = bzr[c], bz = bzr[c+64];
    size_t ii = ((size_t)b*64 + c)*256 + q;
    float4 hv = ((const float4*)h)[ii];
    float4 r, z;
    r.x = sigmoidf_(pr.x+pr2.x+br); r.y = sigmoidf_(pr.y+pr2.y+br);
    r.z = sigmoidf_(pr.z+pr2.z+br); r.w = sigmoidf_(pr.w+pr2.w+br);
    z.x = sigmoidf_(pz.x+pz2.x+bz); z.y = sigmoidf_(pz.y+pz2.y+bz);
    z.z = sigmoidf_(pz.z+pz2.z+bz); z.w = sigmoidf_(pz.w+pz2.w+bz);
    float4 rhv = make_float4(r.x*hv.x, r.y*hv.y, r.z*hv.z, r.w*hv.w);
    ((float4*)rh)[ii] = rhv;
    ((float4*)zout)[ii] = z;
}

// ---------------------------------------------------------------------------
// combine cand: cand=tanh(sum P[0..3]+bc); hn=(1-z)*h+z*cand -> h (and hs[t])
// ---------------------------------------------------------------------------
__global__ __launch_bounds__(256) void k_comb_cand(const float* __restrict__ P,
    const float* __restrict__ h, const float* __restrict__ z, const float* __restrict__ bc,
    float* __restrict__ hout, float* __restrict__ hsout)
{
    int i = blockIdx.x*256 + threadIdx.x;
    int q = i & 255; int c = (i >> 8) & 63; int b = i >> 14;
    size_t ii = ((size_t)b*64 + c)*256 + q;
    size_t s = (size_t)32*64*256;
    const float4* P4 = (const float4*)P;
    float4 p0 = P4[ii], p1 = P4[ii+s], p2 = P4[ii+2*s], p3 = P4[ii+3*s];
    float bcv = bc[c];
    float4 hv = ((const float4*)h)[ii];
    float4 zv = ((const float4*)z)[ii];
    float4 hn;
    float cx = tanhf(p0.x+p1.x+p2.x+p3.x+bcv);
    float cy = tanhf(p0.y+p1.y+p2.y+p3.y+bcv);
    float cz = tanhf(p0.z+p1.z+p2.z+p3.z+bcv);
    float cw = tanhf(p0.w+p1.w+p2.w+p3.w+bcv);
    hn.x = (1.f-zv.x)*hv.x + zv.x*cx;
    hn.y = (1.f-zv.y)*hv.y + zv.y*cy;
    hn.z = (1.f-zv.z)*hv.z + zv.z*cz;
    hn.w = (1.f-zv.w)*hv.w + zv.w*cw;
    ((float4*)hout)[ii] = hn;
    if (hsout) ((float4*)hsout)[ii] = hn;
}

// ---------------------------------------------------------------------------
// deconv1: hs (Ntb,64,32,32) -> y1 (Ntb,32,64,64), k4 lhs_dil2 pad2, bias+lrelu
// ---------------------------------------------------------------------------
__global__ __launch_bounds__(256) void k_deconv1(const float* __restrict__ in,
    const float* __restrict__ W, const float* __restrict__ Bb, float* __restrict__ out)
{
    __shared__ float tile[4*18*44];  // 3168
    __shared__ float wl[4*16*8];     // 512
    int tid = threadIdx.x;
    int tb = blockIdx.z;
    int ocBase = blockIdx.x*8;
    int Y0 = blockIdx.y*32;
    int low = tid & 127;
    int par = tid >> 7;              // wave-uniform parity
    int y = low >> 2, xg = low & 3, x0 = xg*16;
    int oy = Y0 + y;
    int ph = y & 1;
    int r0 = (y+1) >> 1;
    float acc[8][8];
    #pragma unroll
    for (int o=0;o<8;++o)
        #pragma unroll
        for (int j=0;j<8;++j) acc[o][j]=0.f;
    const float* base = in + (size_t)tb*65536;
    int iyBase = Y0/2 - 1;
    for (int icB=0; icB<64; icB+=4){
        for (int e=tid; e<792; e+=256){            // 4*18*11 float4
            int c4 = e % 11; int rr = (e/11)%18; int ch = e/(11*18);
            int iy = iyBase + rr; int ixb = c4*4 - 4;
            float4 v = make_float4(0.f,0.f,0.f,0.f);
            if (iy>=0 && iy<32 && c4>=1 && c4<=8)
                v = *(const float4*)(base + (icB+ch)*1024 + iy*32 + ixb);
            *(float4*)(&tile[ch*792 + rr*44 + c4*4]) = v;
        }
        for (int e=tid; e<512; e+=256){
            int oc = e & 7; int rest = e >> 3; int tap = rest & 15; int ch = rest >> 4;
            wl[(ch*16+tap)*8+oc] = W[(((ocBase+oc)*64) + icB+ch)*16 + tap];
        }
        __syncthreads();
        #pragma unroll
        for (int ch=0; ch<4; ++ch){
            const float4* ra = (const float4*)(&tile[ch*792 + r0*44 + 8*xg]);
            float4 a0=ra[0],a1=ra[1],a2=ra[2],a3=ra[3];
            const float4* rb = (const float4*)(&tile[ch*792 + (r0+1)*44 + 8*xg]);
            float4 b0=rb[0],b1=rb[1],b2=rb[2],b3=rb[3];
            float wa[16]={a0.x,a0.y,a0.z,a0.w,a1.x,a1.y,a1.z,a1.w,
                          a2.x,a2.y,a2.z,a2.w,a3.x,a3.y,a3.z,a3.w};
            float wb[16]={b0.x,b0.y,b0.z,b0.w,b1.x,b1.y,b1.z,b1.w,
                          b2.x,b2.y,b2.z,b2.w,b3.x,b3.y,b3.z,b3.w};
            if (par == 0){
                const float4* wp;
                wp = (const float4*)(&wl[(ch*16+ph*4+0)*8]);     float4 wA0=wp[0], wA1=wp[1];
                wp = (const float4*)(&wl[(ch*16+ph*4+2)*8]);     float4 wB0=wp[0], wB1=wp[1];
                wp = (const float4*)(&wl[(ch*16+(ph+2)*4+0)*8]); float4 wC0=wp[0], wC1=wp[1];
                wp = (const float4*)(&wl[(ch*16+(ph+2)*4+2)*8]); float4 wD0=wp[0], wD1=wp[1];
                #pragma unroll
                for (int j=0;j<8;++j){
                    float v0 = wa[j+3], v1 = wa[j+4], v2 = wb[j+3], v3 = wb[j+4];
                    acc[0][j] += wA0.x*v0 + wB0.x*v1 + wC0.x*v2 + wD0.x*v3;
                    acc[1][j] += wA0.y*v0 + wB0.y*v1 + wC0.y*v2 + wD0.y*v3;
                    acc[2][j] += wA0.z*v0 + wB0.z*v1 + wC0.z*v2 + wD0.z*v3;
                    acc[3][j] += wA0.w*v0 + wB0.w*v1 + wC0.w*v2 + wD0.w*v3;
                    acc[4][j] += wA1.x*v0 + wB1.x*v1 + wC1.x*v2 + wD1.x*v3;
                    acc[5][j] += wA1.y*v0 + wB1.y*v1 + wC1.y*v2 + wD1.y*v3;
                    acc[6][j] += wA1.z*v0 + wB1.z*v1 + wC1.z*v2 + wD1.z*v3;
                    acc[7][j] += wA1.w*v0 + wB1.w*v1 + wC1.w*v2 + wD1.w*v3;
                }
            } else {
                const float4* wp;
                wp = (const float4*)(&wl[(ch*16+ph*4+1)*8]);     float4 wA0=wp[0], wA1=wp[1];
                wp = (const float4*)(&wl[(ch*16+ph*4+3)*8]);     float4 wB0=wp[0], wB1=wp[1];
                wp = (const float4*)(&wl[(ch*16+(ph+2)*4+1)*8]); float4 wC0=wp[0], wC1=wp[1];
                wp = (const float4*)(&wl[(ch*16+(ph+2)*4+3)*8]); float4 wD0=wp[0], wD1=wp[1];
                #pragma unroll
                for (int j=0;j<8;++j){
                    float v0 = wa[j+4], v1 = wa[j+5], v2 = wb[j+4], v3 = wb[j+5];
                    acc[0][j] += wA0.x*v0 + wB0.x*v1 + wC0.x*v2 + wD0.x*v3;
                    acc[1][j] += wA0.y*v0 + wB0.y*v1 + wC0.y*v2 + wD0.y*v3;
                    acc[2][j] += wA0.z*v0 + wB0.z*v1 + wC0.z*v2 + wD0.z*v3;
                    acc[3][j] += wA0.w*v0 + wB0.w*v1 + wC0.w*v2 + wD0.w*v3;
                    acc[4][j] += wA1.x*v0 + wB1.x*v1 + wC1.x*v2 + wD1.x*v3;
                    acc[5][j] += wA1.y*v0 + wB1.y*v1 + wC1.y*v2 + wD1.y*v3;
                    acc[6][j] += wA1.z*v0 + wB1.z*v1 + wC1.z*v2 + wD1.z*v3;
                    acc[7][j] += wA1.w*v0 + wB1.w*v1 + wC1.w*v2 + wD1.w*v3;
                }
            }
        }
        __syncthreads();
    }
    float* op = out + (size_t)tb*131072 + (size_t)ocBase*4096 + oy*64 + x0 + par;
    #pragma unroll
    for (int o=0;o<8;++o){
        float bv = Bb[ocBase+o];
        #pragma unroll
        for (int j=0;j<8;++j){
            float v = acc[o][j] + bv;
            op[o*4096 + 2*j] = LRELU(v);
        }
    }
}

// ---------------------------------------------------------------------------
// deconv2: y1 (Ntb,32,64,64) -> out with (t,b) permute, k4 lhs_dil2 pad2, bias.
// ---------------------------------------------------------------------------
__global__ __launch_bounds__(256) void k_deconv2(const float* __restrict__ in,
    const float* __restrict__ W, const float* __restrict__ Bb, float* __restrict__ out,
    int tbOff)
{
    __shared__ float wl[512];
    int tid = threadIdx.x;
    for (int e=tid; e<512; e+=256) wl[e] = W[e];   // [ic][kh][kw], oc=1
    __syncthreads();
    int tbl = blockIdx.y;
    int tb = tbOff + tbl; int t = tb >> 5; int b = tb & 31;
    int idx4 = blockIdx.x*256 + tid;
    int oy = idx4 >> 5; int ox0 = (idx4 & 31)*4;
    int ph = oy & 1;
    const float* base = in + (size_t)tbl*131072;
    float acc0=0.f, acc1=0.f, acc2=0.f, acc3=0.f;
    int ix0 = ox0/2 - 1;
    for (int ic=0; ic<32; ++ic){
        const float* cp = base + ic*4096;
        #pragma unroll
        for (int kk=0; kk<2; ++kk){
            int kh = ph + 2*kk;
            int iy = (oy + kh - 2) >> 1;
            if (iy < 0 || iy > 63) continue;
            const float* rp = cp + (size_t)iy*64;
            float wv0 = (ix0 >= 0)   ? rp[ix0]   : 0.f;
            float wv1 = rp[ix0+1];
            float wv2 = rp[ix0+2];
            float wv3 = (ix0+3 <= 63) ? rp[ix0+3] : 0.f;
            float w0 = wl[ic*16 + kh*4 + 0];
            float w1 = wl[ic*16 + kh*4 + 1];
            float w2 = wl[ic*16 + kh*4 + 2];
            float w3 = wl[ic*16 + kh*4 + 3];
            acc0 += w0*wv0 + w2*wv1;        // p=0: kw 0,2
            acc2 += w0*wv1 + w2*wv2;        // p=2
            acc1 += w1*wv1 + w3*wv2;        // p=1: kw 1,3
            acc3 += w1*wv2 + w3*wv3;        // p=3
        }
    }
    float bv = Bb[0];
    float4 res = make_float4(acc0+bv, acc1+bv, acc2+bv, acc3+bv);
    float* op = out + ((size_t)(b*10 + t))*16384 + (size_t)oy*128 + ox0;
    *(float4*)op = res;
}

// ---------------------------------------------------------------------------
// Workspace layout (bytes) — peak 142,606,336 B (136 MiB):
//   [0          ,  83886080): e2 (encoder input stack)  /  hs (decoder outputs)
//   [83886080   ,  92274688): h
//   [92274688   , 100663296): zb
//   [100663296  , 109051904): rh
//   [109051904  , 142606336): P (Pzr [2][32][128][1024] / Pc [4][32][64][1024])
//   Phase 1: e1 chunk (40 MB) overlays [83886080, ...); h memset after.
//   Phase 4: y1 chunk (40 MB) overlays same region (h/zb/rh/P dead).
// ---------------------------------------------------------------------------
extern "C" void kernel_launch(void* const* d_in, const int* in_sizes, int n_in,
                              void* d_out, int out_size, void* d_ws, size_t ws_size,
                              hipStream_t stream)
{
    const float* x    = (const float*)d_in[0];
    const float* ew1  = (const float*)d_in[1];
    const float* eb1  = (const float*)d_in[2];
    const float* ew2  = (const float*)d_in[3];
    const float* eb2  = (const float*)d_in[4];
    const float* ewzr = (const float*)d_in[5];
    const float* ebzr = (const float*)d_in[6];
    const float* ewc  = (const float*)d_in[7];
    const float* ebc  = (const float*)d_in[8];
    const float* dwzr = (const float*)d_in[9];
    const float* dbzr = (const float*)d_in[10];
    const float* dwc  = (const float*)d_in[11];
    const float* dbc  = (const float*)d_in[12];
    const float* dw1  = (const float*)d_in[13];
    const float* db1  = (const float*)d_in[14];
    const float* dw2  = (const float*)d_in[15];
    const float* db2  = (const float*)d_in[16];
    float* out = (float*)d_out;
    char* ws = (char*)d_ws;

    float* e2  = (float*)(ws + 0);
    float* h   = (float*)(ws + 83886080UL);
    float* zb  = (float*)(ws + 92274688UL);
    float* rh  = (float*)(ws + 100663296UL);
    float* P   = (float*)(ws + 109051904UL);
    float* e1c = (float*)(ws + 83886080UL);   // phase-1 overlay (40 MB)
    float* hs  = e2;                          // decoder overlay of e2
    float* y1c = (float*)(ws + 83886080UL);   // phase-4 overlay (40 MB)

    // Phase 1: conv1 -> conv2, chunked x2 over images (160 each)
    for (int c=0; c<2; ++c){
        int off = c*160;
        k_conv1<<<dim3(16,160),256,0,stream>>>(x + (size_t)off*16384, ew1, eb1, e1c);
        k_conv2<<<dim3(4,160),256,0,stream>>>(e1c, ew2, eb2, e2 + (size_t)off*65536);
    }

    hipMemsetAsync(h, 0, 8388608UL, stream);    // h0 = zeros (after e1c overlay dies)

    // Phase 2: encoder GRU scan
    for (int t=0; t<10; ++t){
        k_conv5<<<dim3(32,32,2),128,0,stream>>>(e2 + (size_t)t*65536, 64, 655360,
                                                h, 65536, ewzr, 128, 0, 128, 128, P);
        k_comb_zr<<<2048,256,0,stream>>>(P, h, ebzr, rh, zb);
        k_conv5<<<dim3(16,32,4),128,0,stream>>>(e2 + (size_t)t*65536, 64, 655360,
                                                rh, 65536, ewc, 128, 0, 128, 64, P);
        k_comb_cand<<<2048,256,0,stream>>>(P, h, zb, ebc, h, nullptr);
    }
    // Phase 3: decoder GRU scan (weight ic slice [64:128]); hs overlays e2
    for (int t=0; t<10; ++t){
        k_conv5<<<dim3(32,32,2),128,0,stream>>>(h, 64, 65536, nullptr, 0,
                                                dwzr, 128, 64, 64, 128, P);
        k_comb_zr<<<2048,256,0,stream>>>(P, h, dbzr, rh, zb);
        k_conv5<<<dim3(16,32,4),128,0,stream>>>(rh, 64, 65536, nullptr, 0,
                                                dwc, 128, 64, 64, 64, P);
        k_comb_cand<<<2048,256,0,stream>>>(P, h, zb, dbc, h, hs + (size_t)t*2097152);
    }
    // Phase 4: deconv1 -> deconv2, chunked x4 over tb (80 each)
    for (int c=0; c<4; ++c){
        int tbOff = c*80;
        k_deconv1<<<dim3(4,2,80),256,0,stream>>>(hs + (size_t)tbOff*65536, dw1, db1, y1c);
        k_deconv2<<<dim3(16,80),256,0,stream>>>(y1c, dw2, db2, out, tbOff);
    }
}

// Round 4
// 4825.182 us; speedup vs baseline: 2.2100x; 2.2100x over previous
//
#include <hip/hip_runtime.h>
#include <math.h>

#define LRELU(v) ((v) >= 0.f ? (v) : 0.2f*(v))

__device__ __forceinline__ float sigmoidf_(float x){ return 1.f/(1.f + expf(-x)); }

typedef __attribute__((ext_vector_type(8))) short bf16x8;
typedef __attribute__((ext_vector_type(4))) float f32x4;
typedef __attribute__((ext_vector_type(8))) unsigned short u16x8;
typedef __attribute__((ext_vector_type(4))) unsigned short u16x4;

__device__ __forceinline__ unsigned short bf16_rne(float x){
    union { float f; unsigned u; } v; v.f = x;
    unsigned r = v.u + 0x7fffu + ((v.u >> 16) & 1u);
    return (unsigned short)(r >> 16);
}
__device__ __forceinline__ float bf16_tof(unsigned short h){
    union { float f; unsigned u; } v; v.u = ((unsigned)h) << 16; return v.f;
}
__device__ __forceinline__ void bsplit(float x, unsigned short& hi, unsigned short& lo){
    hi = bf16_rne(x);
    lo = bf16_rne(x - bf16_tof(hi));
}

// ---------------------------------------------------------------------------
// conv1: x (Nimg,1,128,128) -> e1 (Nimg,16,64,64) fp32 ch-first, k3 s2 p1.
// ---------------------------------------------------------------------------
__global__ __launch_bounds__(256) void k_conv1(const float* __restrict__ x,
    const float* __restrict__ W, const float* __restrict__ Bb, float* __restrict__ out)
{
    __shared__ float wl[144];
    __shared__ float bl[16];
    int tid = threadIdx.x;
    if (tid < 144) { int oc = tid/9, tap = tid%9; wl[tap*16+oc] = W[oc*9+tap]; }
    if (tid < 16) bl[tid] = Bb[tid];
    __syncthreads();
    int img = blockIdx.y;
    int px = blockIdx.x*256 + tid;
    int oy = px >> 6, ox = px & 63;
    const float* xin = x + (size_t)img*16384;
    float acc[16];
    #pragma unroll
    for (int o=0;o<16;++o) acc[o]=bl[o];
    #pragma unroll
    for (int kh=0; kh<3; ++kh){
        int iy = 2*oy + kh - 1;
        bool vy = (iy>=0 && iy<128);
        #pragma unroll
        for (int kw=0; kw<3; ++kw){
            int ix = 2*ox + kw - 1;
            float v = (vy && ix>=0 && ix<128) ? xin[iy*128+ix] : 0.f;
            int tap = kh*3+kw;
            #pragma unroll
            for (int o=0;o<16;++o) acc[o] += wl[tap*16+o]*v;
        }
    }
    float* op = out + (size_t)img*65536 + px;
    #pragma unroll
    for (int o=0;o<16;++o){ float v = acc[o]; op[o*4096] = LRELU(v); }
}

// ---------------------------------------------------------------------------
// conv2: e1 (Nimg,16,64,64) -> e2 split bf16 hi/lo CHANNEL-LAST [img][1024][64]
// ---------------------------------------------------------------------------
__global__ __launch_bounds__(256) void k_conv2(const float* __restrict__ in,
    const float* __restrict__ W, const float* __restrict__ Bb,
    unsigned short* __restrict__ e2hi, unsigned short* __restrict__ e2lo)
{
    __shared__ float tile[2*65*68];
    __shared__ float wl[2*9*16];
    int tid = threadIdx.x;
    int img = blockIdx.y;
    int ocBase = blockIdx.x*16;
    int y = tid >> 3, xg = tid & 7, x0 = xg*4;
    float acc[16][4];
    #pragma unroll
    for (int o=0;o<16;++o){ float b = Bb[ocBase+o];
        #pragma unroll
        for (int p=0;p<4;++p) acc[o][p] = b; }
    const float* base = in + (size_t)img*65536;
    for (int icB=0; icB<16; icB+=2){
        for (int e=tid; e<2210; e+=256){            // 2*65*17 float4
            int c4 = e % 17; int rr = (e/17)%65; int ch = e/(17*65);
            int iy = rr - 1; int ixb = c4*4 - 4;
            float4 v = make_float4(0.f,0.f,0.f,0.f);
            if (iy>=0 && iy<64 && c4>=1)
                v = *(const float4*)(base + (icB+ch)*4096 + iy*64 + ixb);
            *(float4*)(&tile[ch*4420 + rr*68 + c4*4]) = v;
        }
        for (int e=tid; e<288; e+=256){
            int oc = e & 15; int rest = e >> 4; int tap = rest % 9; int ch = rest/9;
            wl[(ch*9+tap)*16 + oc] = W[((ocBase+oc)*16 + icB+ch)*9 + tap];
        }
        __syncthreads();
        #pragma unroll
        for (int ch=0; ch<2; ++ch){
            #pragma unroll
            for (int kh=0; kh<3; ++kh){
                int r = 2*y + kh;
                const float4* row = (const float4*)(&tile[ch*4420 + r*68 + 2*x0]);
                float4 a0=row[0], a1=row[1], a2=row[2];
                float win[12] = {a0.x,a0.y,a0.z,a0.w,a1.x,a1.y,a1.z,a1.w,a2.x,a2.y,a2.z,a2.w};
                #pragma unroll
                for (int kw=0; kw<3; ++kw){
                    const float4* wp = (const float4*)(&wl[(ch*9+kh*3+kw)*16]);
                    float4 w0=wp[0], w1=wp[1], w2=wp[2], w3=wp[3];
                    float wv[16] = {w0.x,w0.y,w0.z,w0.w,w1.x,w1.y,w1.z,w1.w,
                                    w2.x,w2.y,w2.z,w2.w,w3.x,w3.y,w3.z,w3.w};
                    #pragma unroll
                    for (int p=0;p<4;++p){
                        float v = win[2*p + kw + 3];
                        #pragma unroll
                        for (int o=0;o<16;++o) acc[o][p] += wv[o]*v;
                    }
                }
            }
        }
        __syncthreads();
    }
    size_t pxbase = (size_t)img*1024 + y*32 + x0;
    #pragma unroll
    for (int p=0;p<4;++p){
        u16x8 h0v, h1v, l0v, l1v;
        #pragma unroll
        for (int o=0;o<8;++o){
            float v0 = acc[o][p];   v0 = LRELU(v0);
            float v1 = acc[o+8][p]; v1 = LRELU(v1);
            unsigned short hh, ll;
            bsplit(v0,hh,ll); h0v[o]=hh; l0v[o]=ll;
            bsplit(v1,hh,ll); h1v[o]=hh; l1v[o]=ll;
        }
        size_t bo = (pxbase + p)*64 + ocBase;
        *(u16x8*)&e2hi[bo]   = h0v; *(u16x8*)&e2hi[bo+8] = h1v;
        *(u16x8*)&e2lo[bo]   = l0v; *(u16x8*)&e2lo[bo+8] = l1v;
    }
}

// ---------------------------------------------------------------------------
// k_prep: pack conv5 weights into MFMA A-fragment order, bf16 hi/lo.
// Apack[mt][iccTot][ks=7][lane64][reg8]; oc=mt*16+(lane&15); t=ks*4+(lane>>4);
// ic=icc*8+reg. t>=25 -> zero (tap padding).
// ---------------------------------------------------------------------------
__global__ __launch_bounds__(256) void k_prep(const float* __restrict__ W,
    int wIcTot, int wIcOff, int icTot, int total,
    unsigned short* __restrict__ outHi, unsigned short* __restrict__ outLo)
{
    int id = blockIdx.x*256 + threadIdx.x;
    if (id >= total) return;
    int lane = id & 63;
    int grp  = id >> 6;           // ((mt*iccTot + icc)*7 + ks)
    int ks = grp % 7;
    int rest = grp / 7;
    int iccTot = icTot >> 3;
    int icc = rest % iccTot;
    (void)icc;
    int oc = (rest / iccTot)*16 + (lane & 15);
    int t  = ks*4 + (lane >> 4);
    int icBase = (rest % iccTot)*8;
    u16x8 vh, vl;
    #pragma unroll
    for (int r=0;r<8;++r){
        float v = 0.f;
        if (t < 25) v = W[((size_t)oc*wIcTot + wIcOff + icBase + r)*25 + t];
        unsigned short hh, ll; bsplit(v, hh, ll);
        vh[r]=hh; vl[r]=ll;
    }
    size_t base = ((size_t)grp)*512 + lane*8;
    *(u16x8*)&outHi[base] = vh;
    *(u16x8*)&outLo[base] = vl;
}

// ---------------------------------------------------------------------------
// conv5m: 5x5 pad2 s1 over 32x32 via split-bf16 MFMA shift-GEMM.
// Inputs channel-last bf16 hi/lo: ic chunk icc<iccA from (aHi,aLo,strA),
// else (bHi,bLo,strB). Weights from k_prep pack. Output P fp32 channel-last
// [split][32b][1024px][ocT]. Block 256 = 4 waves; block tile 32oc x 8rows.
// grid (ocT/32, 4, 32*nsplit).
// ---------------------------------------------------------------------------
__global__ __launch_bounds__(256) void k_conv5m(
    const unsigned short* __restrict__ aHi, const unsigned short* __restrict__ aLo,
    unsigned long long strA, int iccA,
    const unsigned short* __restrict__ bHi, const unsigned short* __restrict__ bLo,
    unsigned long long strB,
    const unsigned short* __restrict__ wHi, const unsigned short* __restrict__ wLo,
    int iccTot, int nsplit, int ocT, float* __restrict__ P)
{
    __shared__ __align__(16) unsigned short ldsHi[12*36*8];
    __shared__ __align__(16) unsigned short ldsLo[12*36*8];
    int tid = threadIdx.x;
    int lane = tid & 63, wave = tid >> 6;
    int zb = blockIdx.z; int split = zb >> 5; int b = zb & 31;
    int r0 = blockIdx.y*8;
    int ocBlk = blockIdx.x;
    int iccCnt = iccTot / nsplit;
    int icc0 = split * iccCnt;
    P += (size_t)split * 32 * 1024 * ocT;

    int offs[7];
    #pragma unroll
    for (int ks=0; ks<7; ++ks){
        int t = ks*4 + (lane>>4);
        int dy = (t<25)? t/5 : 2;
        int dx = (t<25)? t%5 : 2;
        offs[ks] = (dy*36 + dx)*8;
    }
    int eb[4];
    #pragma unroll
    for (int n=0;n<4;++n)
        eb[n] = (((wave*2 + (n>>1))*36) + (n&1)*16 + (lane&15))*8;

    f32x4 acc[2][4];
    #pragma unroll
    for (int m=0;m<2;++m)
      #pragma unroll
      for (int n=0;n<4;++n) acc[m][n] = (f32x4){0.f,0.f,0.f,0.f};

    for (int icc = icc0; icc < icc0 + iccCnt; ++icc){
        const unsigned short* sH; const unsigned short* sL; int icLoc;
        if (icc < iccA){ sH = aHi + (size_t)b*strA; sL = aLo + (size_t)b*strA; icLoc = icc; }
        else           { sH = bHi + (size_t)b*strB; sL = bLo + (size_t)b*strB; icLoc = icc - iccA; }
        #pragma unroll
        for (int s0=0; s0<2; ++s0){
            int s = tid + s0*256;
            if (s < 432){
                int ly = s/36, lx = s - ly*36;
                int gy = r0 - 2 + ly, gx = lx - 2;
                u16x8 vh = (u16x8)0, vl = (u16x8)0;
                if (gy>=0 && gy<32 && gx>=0 && gx<32){
                    size_t off = ((size_t)(gy*32+gx))*64 + icLoc*8;
                    vh = *(const u16x8*)&sH[off];
                    vl = *(const u16x8*)&sL[off];
                }
                *(u16x8*)&ldsHi[s*8] = vh;
                *(u16x8*)&ldsLo[s*8] = vl;
            }
        }
        __syncthreads();
        #pragma unroll
        for (int ks=0; ks<7; ++ks){
            size_t i0 = (((size_t)(ocBlk*2+0)*iccTot + icc)*7 + ks)*512 + lane*8;
            size_t i1 = (((size_t)(ocBlk*2+1)*iccTot + icc)*7 + ks)*512 + lane*8;
            bf16x8 a0h = *(const bf16x8*)&wHi[i0];
            bf16x8 a0l = *(const bf16x8*)&wLo[i0];
            bf16x8 a1h = *(const bf16x8*)&wHi[i1];
            bf16x8 a1l = *(const bf16x8*)&wLo[i1];
            bf16x8 bh[4], bl[4];
            #pragma unroll
            for (int n=0;n<4;++n){
                int e = eb[n] + offs[ks];
                bh[n] = *(const bf16x8*)&ldsHi[e];
                bl[n] = *(const bf16x8*)&ldsLo[e];
            }
            #pragma unroll
            for (int n=0;n<4;++n){
                acc[0][n] = __builtin_amdgcn_mfma_f32_16x16x32_bf16(a0h, bh[n], acc[0][n], 0,0,0);
                acc[0][n] = __builtin_amdgcn_mfma_f32_16x16x32_bf16(a0h, bl[n], acc[0][n], 0,0,0);
                acc[0][n] = __builtin_amdgcn_mfma_f32_16x16x32_bf16(a0l, bh[n], acc[0][n], 0,0,0);
                acc[1][n] = __builtin_amdgcn_mfma_f32_16x16x32_bf16(a1h, bh[n], acc[1][n], 0,0,0);
                acc[1][n] = __builtin_amdgcn_mfma_f32_16x16x32_bf16(a1h, bl[n], acc[1][n], 0,0,0);
                acc[1][n] = __builtin_amdgcn_mfma_f32_16x16x32_bf16(a1l, bh[n], acc[1][n], 0,0,0);
            }
        }
        __syncthreads();
    }
    #pragma unroll
    for (int m=0;m<2;++m){
        #pragma unroll
        for (int n=0;n<4;++n){
            int px = (r0 + wave*2 + (n>>1))*32 + (n&1)*16 + (lane&15);
            float* dst = P + ((size_t)b*1024 + px)*ocT + ocBlk*32 + m*16 + (lane>>4)*4;
            *(f32x4*)dst = acc[m][n];
        }
    }
}

// ---------------------------------------------------------------------------
// comb_zr2 (channel-last): r=sig(P[:,0:64]+br), z=sig(P[:,64:128]+bz);
// writes z32 fp32, rh split bf16 hi/lo. thread: (px, 4 oc).
// ---------------------------------------------------------------------------
__global__ __launch_bounds__(256) void k_comb_zr2(const float* __restrict__ P,
    const float* __restrict__ h32, const float* __restrict__ bzr,
    float* __restrict__ z32, unsigned short* __restrict__ rhHi,
    unsigned short* __restrict__ rhLo)
{
    int i = blockIdx.x*256 + threadIdx.x;       // 524288 threads
    int oc4 = i & 15; int pxg = i >> 4;
    f32x4 pr = *(const f32x4*)&P[(size_t)pxg*128 + oc4*4];
    f32x4 pz = *(const f32x4*)&P[(size_t)pxg*128 + 64 + oc4*4];
    f32x4 h4 = *(const f32x4*)&h32[(size_t)pxg*64 + oc4*4];
    f32x4 br = *(const f32x4*)&bzr[oc4*4];
    f32x4 bz = *(const f32x4*)&bzr[64 + oc4*4];
    f32x4 z;
    u16x4 rhH, rhL;
    #pragma unroll
    for (int j=0;j<4;++j){
        float r = sigmoidf_(pr[j] + br[j]);
        z[j] = sigmoidf_(pz[j] + bz[j]);
        unsigned short hh, ll; bsplit(r * h4[j], hh, ll);
        rhH[j]=hh; rhL[j]=ll;
    }
    *(f32x4*)&z32[(size_t)pxg*64 + oc4*4] = z;
    *(u16x4*)&rhHi[(size_t)pxg*64 + oc4*4] = rhH;
    *(u16x4*)&rhLo[(size_t)pxg*64 + oc4*4] = rhL;
}

// ---------------------------------------------------------------------------
// comb_cand2: cand=tanh(P0+P1+bc); hn=(1-z)h+z*cand. Writes h32, h hi/lo,
// optionally hs (channel-FIRST fp32 for deconv1).
// ---------------------------------------------------------------------------
__global__ __launch_bounds__(256) void k_comb_cand2(const float* __restrict__ P,
    const float* __restrict__ h32, const float* __restrict__ z32,
    const float* __restrict__ bc,
    float* __restrict__ hOut, unsigned short* __restrict__ hHi,
    unsigned short* __restrict__ hLo, float* __restrict__ hsOut)
{
    int i = blockIdx.x*256 + threadIdx.x;
    int oc4 = i & 15; int pxg = i >> 4;
    size_t ii = (size_t)pxg*64 + oc4*4;
    f32x4 p0 = *(const f32x4*)&P[ii];
    f32x4 p1 = *(const f32x4*)&P[ii + (size_t)32*1024*64];
    f32x4 h4 = *(const f32x4*)&h32[ii];
    f32x4 z4 = *(const f32x4*)&z32[ii];
    f32x4 b4 = *(const f32x4*)&bc[oc4*4];
    f32x4 hn;
    u16x4 hh4, hl4;
    #pragma unroll
    for (int j=0;j<4;++j){
        float c = tanhf(p0[j]+p1[j]+b4[j]);
        hn[j] = (1.f - z4[j])*h4[j] + z4[j]*c;
        unsigned short hh, ll; bsplit(hn[j], hh, ll);
        hh4[j]=hh; hl4[j]=ll;
    }
    *(f32x4*)&hOut[ii] = hn;
    *(u16x4*)&hHi[ii] = hh4;
    *(u16x4*)&hLo[ii] = hl4;
    if (hsOut){
        int b = pxg >> 10; int px = pxg & 1023;
        #pragma unroll
        for (int j=0;j<4;++j)
            hsOut[(size_t)b*65536 + (size_t)(oc4*4+j)*1024 + px] = hn[j];
    }
}

// ---------------------------------------------------------------------------
// deconv1: hs (Ntb,64,32,32) -> y1 (Ntb,32,64,64), k4 lhs_dil2 pad2, bias+lrelu
// ---------------------------------------------------------------------------
__global__ __launch_bounds__(256) void k_deconv1(const float* __restrict__ in,
    const float* __restrict__ W, const float* __restrict__ Bb, float* __restrict__ out)
{
    __shared__ float tile[4*18*44];  // 3168
    __shared__ float wl[4*16*8];     // 512
    int tid = threadIdx.x;
    int tb = blockIdx.z;
    int ocBase = blockIdx.x*8;
    int Y0 = blockIdx.y*32;
    int low = tid & 127;
    int par = tid >> 7;              // wave-uniform parity
    int y = low >> 2, xg = low & 3, x0 = xg*16;
    int oy = Y0 + y;
    int ph = y & 1;
    int r0 = (y+1) >> 1;
    float acc[8][8];
    #pragma unroll
    for (int o=0;o<8;++o)
        #pragma unroll
        for (int j=0;j<8;++j) acc[o][j]=0.f;
    const float* base = in + (size_t)tb*65536;
    int iyBase = Y0/2 - 1;
    for (int icB=0; icB<64; icB+=4){
        for (int e=tid; e<792; e+=256){            // 4*18*11 float4
            int c4 = e % 11; int rr = (e/11)%18; int ch = e/(11*18);
            int iy = iyBase + rr; int ixb = c4*4 - 4;
            float4 v = make_float4(0.f,0.f,0.f,0.f);
            if (iy>=0 && iy<32 && c4>=1 && c4<=8)
                v = *(const float4*)(base + (icB+ch)*1024 + iy*32 + ixb);
            *(float4*)(&tile[ch*792 + rr*44 + c4*4]) = v;
        }
        for (int e=tid; e<512; e+=256){
            int oc = e & 7; int rest = e >> 3; int tap = rest & 15; int ch = rest >> 4;
            wl[(ch*16+tap)*8+oc] = W[(((ocBase+oc)*64) + icB+ch)*16 + tap];
        }
        __syncthreads();
        #pragma unroll
        for (int ch=0; ch<4; ++ch){
            const float4* ra = (const float4*)(&tile[ch*792 + r0*44 + 8*xg]);
            float4 a0=ra[0],a1=ra[1],a2=ra[2],a3=ra[3];
            const float4* rb = (const float4*)(&tile[ch*792 + (r0+1)*44 + 8*xg]);
            float4 b0=rb[0],b1=rb[1],b2=rb[2],b3=rb[3];
            float wa[16]={a0.x,a0.y,a0.z,a0.w,a1.x,a1.y,a1.z,a1.w,
                          a2.x,a2.y,a2.z,a2.w,a3.x,a3.y,a3.z,a3.w};
            float wb[16]={b0.x,b0.y,b0.z,b0.w,b1.x,b1.y,b1.z,b1.w,
                          b2.x,b2.y,b2.z,b2.w,b3.x,b3.y,b3.z,b3.w};
            if (par == 0){
                const float4* wp;
                wp = (const float4*)(&wl[(ch*16+ph*4+0)*8]);     float4 wA0=wp[0], wA1=wp[1];
                wp = (const float4*)(&wl[(ch*16+ph*4+2)*8]);     float4 wB0=wp[0], wB1=wp[1];
                wp = (const float4*)(&wl[(ch*16+(ph+2)*4+0)*8]); float4 wC0=wp[0], wC1=wp[1];
                wp = (const float4*)(&wl[(ch*16+(ph+2)*4+2)*8]); float4 wD0=wp[0], wD1=wp[1];
                #pragma unroll
                for (int j=0;j<8;++j){
                    float v0 = wa[j+3], v1 = wa[j+4], v2 = wb[j+3], v3 = wb[j+4];
                    acc[0][j] += wA0.x*v0 + wB0.x*v1 + wC0.x*v2 + wD0.x*v3;
                    acc[1][j] += wA0.y*v0 + wB0.y*v1 + wC0.y*v2 + wD0.y*v3;
                    acc[2][j] += wA0.z*v0 + wB0.z*v1 + wC0.z*v2 + wD0.z*v3;
                    acc[3][j] += wA0.w*v0 + wB0.w*v1 + wC0.w*v2 + wD0.w*v3;
                    acc[4][j] += wA1.x*v0 + wB1.x*v1 + wC1.x*v2 + wD1.x*v3;
                    acc[5][j] += wA1.y*v0 + wB1.y*v1 + wC1.y*v2 + wD1.y*v3;
                    acc[6][j] += wA1.z*v0 + wB1.z*v1 + wC1.z*v2 + wD1.z*v3;
                    acc[7][j] += wA1.w*v0 + wB1.w*v1 + wC1.w*v2 + wD1.w*v3;
                }
            } else {
                const float4* wp;
                wp = (const float4*)(&wl[(ch*16+ph*4+1)*8]);     float4 wA0=wp[0], wA1=wp[1];
                wp = (const float4*)(&wl[(ch*16+ph*4+3)*8]);     float4 wB0=wp[0], wB1=wp[1];
                wp = (const float4*)(&wl[(ch*16+(ph+2)*4+1)*8]); float4 wC0=wp[0], wC1=wp[1];
                wp = (const float4*)(&wl[(ch*16+(ph+2)*4+3)*8]); float4 wD0=wp[0], wD1=wp[1];
                #pragma unroll
                for (int j=0;j<8;++j){
                    float v0 = wa[j+4], v1 = wa[j+5], v2 = wb[j+4], v3 = wb[j+5];
                    acc[0][j] += wA0.x*v0 + wB0.x*v1 + wC0.x*v2 + wD0.x*v3;
                    acc[1][j] += wA0.y*v0 + wB0.y*v1 + wC0.y*v2 + wD0.y*v3;
                    acc[2][j] += wA0.z*v0 + wB0.z*v1 + wC0.z*v2 + wD0.z*v3;
                    acc[3][j] += wA0.w*v0 + wB0.w*v1 + wC0.w*v2 + wD0.w*v3;
                    acc[4][j] += wA1.x*v0 + wB1.x*v1 + wC1.x*v2 + wD1.x*v3;
                    acc[5][j] += wA1.y*v0 + wB1.y*v1 + wC1.y*v2 + wD1.y*v3;
                    acc[6][j] += wA1.z*v0 + wB1.z*v1 + wC1.z*v2 + wD1.z*v3;
                    acc[7][j] += wA1.w*v0 + wB1.w*v1 + wC1.w*v2 + wD1.w*v3;
                }
            }
        }
        __syncthreads();
    }
    float* op = out + (size_t)tb*131072 + (size_t)ocBase*4096 + oy*64 + x0 + par;
    #pragma unroll
    for (int o=0;o<8;++o){
        float bv = Bb[ocBase+o];
        #pragma unroll
        for (int j=0;j<8;++j){
            float v = acc[o][j] + bv;
            op[o*4096 + 2*j] = LRELU(v);
        }
    }
}

// ---------------------------------------------------------------------------
// deconv2: y1 (Ntb,32,64,64) -> out with (t,b) permute, k4 lhs_dil2 pad2, bias.
// ---------------------------------------------------------------------------
__global__ __launch_bounds__(256) void k_deconv2(const float* __restrict__ in,
    const float* __restrict__ W, const float* __restrict__ Bb, float* __restrict__ out,
    int tbOff)
{
    __shared__ float wl[512];
    int tid = threadIdx.x;
    for (int e=tid; e<512; e+=256) wl[e] = W[e];   // [ic][kh][kw], oc=1
    __syncthreads();
    int tbl = blockIdx.y;
    int tb = tbOff + tbl; int t = tb >> 5; int b = tb & 31;
    int idx4 = blockIdx.x*256 + tid;
    int oy = idx4 >> 5; int ox0 = (idx4 & 31)*4;
    int ph = oy & 1;
    const float* base = in + (size_t)tbl*131072;
    float acc0=0.f, acc1=0.f, acc2=0.f, acc3=0.f;
    int ix0 = ox0/2 - 1;
    for (int ic=0; ic<32; ++ic){
        const float* cp = base + ic*4096;
        #pragma unroll
        for (int kk=0; kk<2; ++kk){
            int kh = ph + 2*kk;
            int iy = (oy + kh - 2) >> 1;
            if (iy < 0 || iy > 63) continue;
            const float* rp = cp + (size_t)iy*64;
            float wv0 = (ix0 >= 0)   ? rp[ix0]   : 0.f;
            float wv1 = rp[ix0+1];
            float wv2 = rp[ix0+2];
            float wv3 = (ix0+3 <= 63) ? rp[ix0+3] : 0.f;
            float w0 = wl[ic*16 + kh*4 + 0];
            float w1 = wl[ic*16 + kh*4 + 1];
            float w2 = wl[ic*16 + kh*4 + 2];
            float w3 = wl[ic*16 + kh*4 + 3];
            acc0 += w0*wv0 + w2*wv1;        // p=0: kw 0,2
            acc2 += w0*wv1 + w2*wv2;        // p=2
            acc1 += w1*wv1 + w3*wv2;        // p=1: kw 1,3
            acc3 += w1*wv2 + w3*wv3;        // p=3
        }
    }
    float bv = Bb[0];
    float4 res = make_float4(acc0+bv, acc1+bv, acc2+bv, acc3+bv);
    float* op = out + ((size_t)(b*10 + t))*16384 + (size_t)oy*128 + ox0;
    *(float4*)op = res;
}

// ---------------------------------------------------------------------------
// Workspace (bytes), peak 138,346,496:
//  [0        , 41943040): e2s_hi [320][1024][64] bf16   / hs overlay (dec)
//  [41943040 , 83886080): e2s_lo                        / hs overlay cont'd
//  [83886080 , 92274688): h32    [32][1024][64] fp32
//  [92274688 , 96468992): h_hi   bf16
//  [96468992 ,100663296): h_lo
//  [100663296,104857600): rh_hi
//  [104857600,109051904): rh_lo
//  [109051904,117440512): z32
//  [117440512,134217728): P (up to [2][32][1024][64] or [1][32][1024][128])
//  [134217728,138346496): Apack (4 weight sets, hi|lo each)
//  Phase 1 e1c overlay / Phase 4 y1c overlay: [83886080, 125829120) region
//  (h*/rh/z/P) — dead during those phases; h memsets run after phase 1.
// ---------------------------------------------------------------------------
extern "C" void kernel_launch(void* const* d_in, const int* in_sizes, int n_in,
                              void* d_out, int out_size, void* d_ws, size_t ws_size,
                              hipStream_t stream)
{
    const float* x    = (const float*)d_in[0];
    const float* ew1  = (const float*)d_in[1];
    const float* eb1  = (const float*)d_in[2];
    const float* ew2  = (const float*)d_in[3];
    const float* eb2  = (const float*)d_in[4];
    const float* ewzr = (const float*)d_in[5];
    const float* ebzr = (const float*)d_in[6];
    const float* ewc  = (const float*)d_in[7];
    const float* ebc  = (const float*)d_in[8];
    const float* dwzr = (const float*)d_in[9];
    const float* dbzr = (const float*)d_in[10];
    const float* dwc  = (const float*)d_in[11];
    const float* dbc  = (const float*)d_in[12];
    const float* dw1  = (const float*)d_in[13];
    const float* db1  = (const float*)d_in[14];
    const float* dw2  = (const float*)d_in[15];
    const float* db2  = (const float*)d_in[16];
    float* out = (float*)d_out;
    char* ws = (char*)d_ws;

    unsigned short* e2hi = (unsigned short*)(ws + 0);
    unsigned short* e2lo = (unsigned short*)(ws + 41943040UL);
    float*          h32  = (float*)(ws + 83886080UL);
    unsigned short* hHi  = (unsigned short*)(ws + 92274688UL);
    unsigned short* hLo  = (unsigned short*)(ws + 96468992UL);
    unsigned short* rhHi = (unsigned short*)(ws + 100663296UL);
    unsigned short* rhLo = (unsigned short*)(ws + 104857600UL);
    float*          z32  = (float*)(ws + 109051904UL);
    float*          P    = (float*)(ws + 117440512UL);
    unsigned short* A0   = (unsigned short*)(ws + 134217728UL);
    unsigned short* AzrH = A0;            unsigned short* AzrL = A0 + 458752;
    unsigned short* AcH  = A0 + 917504;   unsigned short* AcL  = A0 + 1146880;
    unsigned short* DzrH = A0 + 1376256;  unsigned short* DzrL = A0 + 1605632;
    unsigned short* DcH  = A0 + 1835008;  unsigned short* DcL  = A0 + 1949696;
    float* e1c = (float*)(ws + 83886080UL);   // phase-1 overlay (40 MB)
    float* hs  = (float*)(ws + 0);            // decoder overlay of e2s
    float* y1c = (float*)(ws + 83886080UL);   // phase-4 overlay (40 MB)

    // Weight packing (runs every call; ~10 us total)
    k_prep<<<224,256,0,stream>>>(ewzr, 128, 0, 128, 57344, AzrH, AzrL);
    k_prep<<<112,256,0,stream>>>(ewc,  128, 0, 128, 28672, AcH,  AcL);
    k_prep<<<112,256,0,stream>>>(dwzr, 128, 64, 64, 28672, DzrH, DzrL);
    k_prep<<< 56,256,0,stream>>>(dwc,  128, 64, 64, 14336, DcH,  DcL);

    // Phase 1: conv1 -> conv2 (writes e2 split, channel-last), chunked x2
    for (int c=0; c<2; ++c){
        int off = c*160;
        k_conv1<<<dim3(16,160),256,0,stream>>>(x + (size_t)off*16384, ew1, eb1, e1c);
        k_conv2<<<dim3(4,160),256,0,stream>>>(e1c, ew2, eb2,
                                              e2hi + (size_t)off*65536,
                                              e2lo + (size_t)off*65536);
    }

    hipMemsetAsync(h32, 0, 8388608UL, stream);
    hipMemsetAsync(hHi, 0, 4194304UL, stream);
    hipMemsetAsync(hLo, 0, 4194304UL, stream);

    // Phase 2: encoder GRU scan
    for (int t=0; t<10; ++t){
        k_conv5m<<<dim3(4,4,32),256,0,stream>>>(
            e2hi + (size_t)t*65536, e2lo + (size_t)t*65536, 655360ULL, 8,
            hHi, hLo, 65536ULL, AzrH, AzrL, 16, 1, 128, P);
        k_comb_zr2<<<2048,256,0,stream>>>(P, h32, ebzr, z32, rhHi, rhLo);
        k_conv5m<<<dim3(2,4,64),256,0,stream>>>(
            e2hi + (size_t)t*65536, e2lo + (size_t)t*65536, 655360ULL, 8,
            rhHi, rhLo, 65536ULL, AcH, AcL, 16, 2, 64, P);
        k_comb_cand2<<<2048,256,0,stream>>>(P, h32, z32, ebc, h32, hHi, hLo, nullptr);
    }
    // Phase 3: decoder GRU scan; hs overlays e2s
    for (int t=0; t<10; ++t){
        k_conv5m<<<dim3(4,4,32),256,0,stream>>>(
            hHi, hLo, 65536ULL, 8,
            hHi, hLo, 65536ULL, DzrH, DzrL, 8, 1, 128, P);
        k_comb_zr2<<<2048,256,0,stream>>>(P, h32, dbzr, z32, rhHi, rhLo);
        k_conv5m<<<dim3(2,4,64),256,0,stream>>>(
            rhHi, rhLo, 65536ULL, 8,
            rhHi, rhLo, 65536ULL, DcH, DcL, 8, 2, 64, P);
        k_comb_cand2<<<2048,256,0,stream>>>(P, h32, z32, dbc, h32, hHi, hLo,
                                            hs + (size_t)t*2097152);
    }
    // Phase 4: deconv1 -> deconv2, chunked x4 over tb (80 each)
    for (int c=0; c<4; ++c){
        int tbOff = c*80;
        k_deconv1<<<dim3(4,2,80),256,0,stream>>>(hs + (size_t)tbOff*65536, dw1, db1, y1c);
        k_deconv2<<<dim3(16,80),256,0,stream>>>(y1c, dw2, db2, out, tbOff);
    }
}

// Round 5
// 4530.902 us; speedup vs baseline: 2.3536x; 1.0649x over previous
//
#include <hip/hip_runtime.h>
#include <math.h>

#define LRELU(v) ((v) >= 0.f ? (v) : 0.2f*(v))

__device__ __forceinline__ float sigmoidf_(float x){ return 1.f/(1.f + expf(-x)); }

typedef __attribute__((ext_vector_type(8))) short bf16x8;
typedef __attribute__((ext_vector_type(4))) float f32x4;
typedef __attribute__((ext_vector_type(8))) unsigned short u16x8;
typedef __attribute__((ext_vector_type(4))) unsigned short u16x4;

__device__ __forceinline__ unsigned short bf16_rne(float x){
    union { float f; unsigned u; } v; v.f = x;
    unsigned r = v.u + 0x7fffu + ((v.u >> 16) & 1u);
    return (unsigned short)(r >> 16);
}
__device__ __forceinline__ float bf16_tof(unsigned short h){
    union { float f; unsigned u; } v; v.u = ((unsigned)h) << 16; return v.f;
}
__device__ __forceinline__ void bsplit(float x, unsigned short& hi, unsigned short& lo){
    hi = bf16_rne(x);
    lo = bf16_rne(x - bf16_tof(hi));
}

// ---------------------------------------------------------------------------
// conv1: x (Nimg,1,128,128) -> e1 (Nimg,16,64,64) fp32 ch-first, k3 s2 p1.
// ---------------------------------------------------------------------------
__global__ __launch_bounds__(256) void k_conv1(const float* __restrict__ x,
    const float* __restrict__ W, const float* __restrict__ Bb, float* __restrict__ out)
{
    __shared__ float wl[144];
    __shared__ float bl[16];
    int tid = threadIdx.x;
    if (tid < 144) { int oc = tid/9, tap = tid%9; wl[tap*16+oc] = W[oc*9+tap]; }
    if (tid < 16) bl[tid] = Bb[tid];
    __syncthreads();
    int img = blockIdx.y;
    int px = blockIdx.x*256 + tid;
    int oy = px >> 6, ox = px & 63;
    const float* xin = x + (size_t)img*16384;
    float acc[16];
    #pragma unroll
    for (int o=0;o<16;++o) acc[o]=bl[o];
    #pragma unroll
    for (int kh=0; kh<3; ++kh){
        int iy = 2*oy + kh - 1;
        bool vy = (iy>=0 && iy<128);
        #pragma unroll
        for (int kw=0; kw<3; ++kw){
            int ix = 2*ox + kw - 1;
            float v = (vy && ix>=0 && ix<128) ? xin[iy*128+ix] : 0.f;
            int tap = kh*3+kw;
            #pragma unroll
            for (int o=0;o<16;++o) acc[o] += wl[tap*16+o]*v;
        }
    }
    float* op = out + (size_t)img*65536 + px;
    #pragma unroll
    for (int o=0;o<16;++o){ float v = acc[o]; op[o*4096] = LRELU(v); }
}

// ---------------------------------------------------------------------------
// conv2: e1 (Nimg,16,64,64) -> e2 split bf16 hi/lo CHANNEL-LAST [img][1024][64]
// ---------------------------------------------------------------------------
__global__ __launch_bounds__(256) void k_conv2(const float* __restrict__ in,
    const float* __restrict__ W, const float* __restrict__ Bb,
    unsigned short* __restrict__ e2hi, unsigned short* __restrict__ e2lo)
{
    __shared__ float tile[2*65*68];
    __shared__ float wl[2*9*16];
    int tid = threadIdx.x;
    int img = blockIdx.y;
    int ocBase = blockIdx.x*16;
    int y = tid >> 3, xg = tid & 7, x0 = xg*4;
    float acc[16][4];
    #pragma unroll
    for (int o=0;o<16;++o){ float b = Bb[ocBase+o];
        #pragma unroll
        for (int p=0;p<4;++p) acc[o][p] = b; }
    const float* base = in + (size_t)img*65536;
    for (int icB=0; icB<16; icB+=2){
        for (int e=tid; e<2210; e+=256){            // 2*65*17 float4
            int c4 = e % 17; int rr = (e/17)%65; int ch = e/(17*65);
            int iy = rr - 1; int ixb = c4*4 - 4;
            float4 v = make_float4(0.f,0.f,0.f,0.f);
            if (iy>=0 && iy<64 && c4>=1)
                v = *(const float4*)(base + (icB+ch)*4096 + iy*64 + ixb);
            *(float4*)(&tile[ch*4420 + rr*68 + c4*4]) = v;
        }
        for (int e=tid; e<288; e+=256){
            int oc = e & 15; int rest = e >> 4; int tap = rest % 9; int ch = rest/9;
            wl[(ch*9+tap)*16 + oc] = W[((ocBase+oc)*16 + icB+ch)*9 + tap];
        }
        __syncthreads();
        #pragma unroll
        for (int ch=0; ch<2; ++ch){
            #pragma unroll
            for (int kh=0; kh<3; ++kh){
                int r = 2*y + kh;
                const float4* row = (const float4*)(&tile[ch*4420 + r*68 + 2*x0]);
                float4 a0=row[0], a1=row[1], a2=row[2];
                float win[12] = {a0.x,a0.y,a0.z,a0.w,a1.x,a1.y,a1.z,a1.w,a2.x,a2.y,a2.z,a2.w};
                #pragma unroll
                for (int kw=0; kw<3; ++kw){
                    const float4* wp = (const float4*)(&wl[(ch*9+kh*3+kw)*16]);
                    float4 w0=wp[0], w1=wp[1], w2=wp[2], w3=wp[3];
                    float wv[16] = {w0.x,w0.y,w0.z,w0.w,w1.x,w1.y,w1.z,w1.w,
                                    w2.x,w2.y,w2.z,w2.w,w3.x,w3.y,w3.z,w3.w};
                    #pragma unroll
                    for (int p=0;p<4;++p){
                        float v = win[2*p + kw + 3];
                        #pragma unroll
                        for (int o=0;o<16;++o) acc[o][p] += wv[o]*v;
                    }
                }
            }
        }
        __syncthreads();
    }
    size_t pxbase = (size_t)img*1024 + y*32 + x0;
    #pragma unroll
    for (int p=0;p<4;++p){
        u16x8 h0v, h1v, l0v, l1v;
        #pragma unroll
        for (int o=0;o<8;++o){
            float v0 = acc[o][p];   v0 = LRELU(v0);
            float v1 = acc[o+8][p]; v1 = LRELU(v1);
            unsigned short hh, ll;
            bsplit(v0,hh,ll); h0v[o]=hh; l0v[o]=ll;
            bsplit(v1,hh,ll); h1v[o]=hh; l1v[o]=ll;
        }
        size_t bo = (pxbase + p)*64 + ocBase;
        *(u16x8*)&e2hi[bo]   = h0v; *(u16x8*)&e2hi[bo+8] = h1v;
        *(u16x8*)&e2lo[bo]   = l0v; *(u16x8*)&e2lo[bo+8] = l1v;
    }
}

// ---------------------------------------------------------------------------
// k_prep: pack conv5 weights into MFMA A-fragment order, bf16 hi/lo.
// grp = ((mt*iccTot + icc)*7 + ks); oc=mt*16+(lane&15); t=ks*4+(lane>>4);
// ic=icc*8+reg; t>=25 -> zero.
// ---------------------------------------------------------------------------
__global__ __launch_bounds__(256) void k_prep(const float* __restrict__ W,
    int wIcTot, int wIcOff, int icTot, int total,
    unsigned short* __restrict__ outHi, unsigned short* __restrict__ outLo)
{
    int id = blockIdx.x*256 + threadIdx.x;
    if (id >= total) return;
    int lane = id & 63;
    int grp  = id >> 6;
    int ks = grp % 7;
    int rest = grp / 7;
    int iccTot = icTot >> 3;
    int oc = (rest / iccTot)*16 + (lane & 15);
    int t  = ks*4 + (lane >> 4);
    int icBase = (rest % iccTot)*8;
    u16x8 vh, vl;
    #pragma unroll
    for (int r=0;r<8;++r){
        float v = 0.f;
        if (t < 25) v = W[((size_t)oc*wIcTot + wIcOff + icBase + r)*25 + t];
        unsigned short hh, ll; bsplit(v, hh, ll);
        vh[r]=hh; vl[r]=ll;
    }
    size_t base = ((size_t)grp)*512 + lane*8;
    *(u16x8*)&outHi[base] = vh;
    *(u16x8*)&outLo[base] = vl;
}

// ---------------------------------------------------------------------------
// k_prep_d1: pack deconv1 (4x4, lhs_dil 2) weights per parity class.
// grp = ((mt*4 + par)*8 + icc); oc=mt*16+(lane&15); t=lane>>4 (a=t>>1,b=t&1);
// kh=2a+py, kw=2b+px; ic=icc*8+reg. W (32,64,4,4).
// ---------------------------------------------------------------------------
__global__ __launch_bounds__(256) void k_prep_d1(const float* __restrict__ W,
    unsigned short* __restrict__ outHi, unsigned short* __restrict__ outLo)
{
    int id = blockIdx.x*256 + threadIdx.x;
    if (id >= 4096) return;
    int lane = id & 63;
    int grp = id >> 6;
    int icc = grp & 7; int par = (grp>>3)&3; int mt = grp>>5;
    int py = par>>1, px = par&1;
    int oc = mt*16 + (lane&15);
    int t = lane>>4; int a = t>>1, bb = t&1;
    int kh = 2*a+py, kw = 2*bb+px;
    u16x8 vh, vl;
    #pragma unroll
    for (int r=0;r<8;++r){
        int ic = icc*8 + r;
        float v = W[(((size_t)oc*64 + ic)*4 + kh)*4 + kw];
        unsigned short hh, ll; bsplit(v, hh, ll);
        vh[r]=hh; vl[r]=ll;
    }
    size_t base = ((size_t)grp)*512 + lane*8;
    *(u16x8*)&outHi[base] = vh;
    *(u16x8*)&outLo[base] = vl;
}

// ---------------------------------------------------------------------------
// k_conv5f: 5x5 pad2 s1 over 32x32, split-bf16 MFMA shift-GEMM with FUSED
// GRU pointwise epilogue. MODE 0 = zr (ocT=128): blocks x<2 -> r=sig(.)+rh
// write; x>=2 -> z=sig(.) write. MODE 1 = cand (ocT=64): hn=(1-z)h+z*tanh(.),
// writes h32/hHi/hLo and optional hs (bf16 hi/lo, channel-last).
// Block 256 = 4 waves; 32oc x (ROWS x 32) px. grid (ocT/32, 32/ROWS, 32).
// ---------------------------------------------------------------------------
template<int MODE, int ROWS>
__global__ __launch_bounds__(256) void k_conv5f(
    const unsigned short* __restrict__ aHi, const unsigned short* __restrict__ aLo,
    unsigned long long strA, int iccA,
    const unsigned short* __restrict__ inbHi, const unsigned short* __restrict__ inbLo,
    unsigned long long strB,
    const unsigned short* __restrict__ wHi, const unsigned short* __restrict__ wLo,
    int iccTot,
    const float* __restrict__ bias,
    const float* __restrict__ h32,
    const float* __restrict__ z32in,
    float* __restrict__ z32out,
    unsigned short* __restrict__ oHi, unsigned short* __restrict__ oLo,
    float* __restrict__ h32out,
    unsigned short* __restrict__ hsHi, unsigned short* __restrict__ hsLo)
{
    constexpr int RW = ROWS/4;          // rows per wave
    constexpr int NT = ROWS/2;          // n-tiles per wave
    constexpr int SPOS = (ROWS+4)*36;
    __shared__ __align__(16) unsigned short ldsHi[SPOS*8];
    __shared__ __align__(16) unsigned short ldsLo[SPOS*8];
    int tid = threadIdx.x;
    int lane = tid & 63, wave = tid >> 6;
    int batch = blockIdx.z;
    int r0 = blockIdx.y*ROWS;
    int ocBlk = blockIdx.x;

    int offs[7];
    #pragma unroll
    for (int ks=0; ks<7; ++ks){
        int t = ks*4 + (lane>>4);
        int dy = (t<25)? t/5 : 2;
        int dx = (t<25)? t%5 : 2;
        offs[ks] = (dy*36 + dx)*8;
    }
    int eb[NT];
    #pragma unroll
    for (int n=0;n<NT;++n)
        eb[n] = (((wave*RW + (n>>1))*36) + (n&1)*16 + (lane&15))*8;

    f32x4 acc[2][NT];
    #pragma unroll
    for (int m=0;m<2;++m)
      #pragma unroll
      for (int n=0;n<NT;++n) acc[m][n] = (f32x4){0.f,0.f,0.f,0.f};

    for (int icc = 0; icc < iccTot; ++icc){
        const unsigned short* sH; const unsigned short* sL; int icLoc;
        if (icc < iccA){ sH = aHi + (size_t)batch*strA; sL = aLo + (size_t)batch*strA; icLoc = icc; }
        else           { sH = inbHi + (size_t)batch*strB; sL = inbLo + (size_t)batch*strB; icLoc = icc - iccA; }
        #pragma unroll
        for (int s0=0; s0<2; ++s0){
            int s = tid + s0*256;
            if (s < SPOS){
                int ly = s/36, lx = s - ly*36;
                int gy = r0 - 2 + ly, gx = lx - 2;
                u16x8 vh = (u16x8)0, vl = (u16x8)0;
                if (gy>=0 && gy<32 && gx>=0 && gx<32){
                    size_t off = ((size_t)(gy*32+gx))*64 + icLoc*8;
                    vh = *(const u16x8*)&sH[off];
                    vl = *(const u16x8*)&sL[off];
                }
                *(u16x8*)&ldsHi[s*8] = vh;
                *(u16x8*)&ldsLo[s*8] = vl;
            }
        }
        __syncthreads();
        #pragma unroll
        for (int ks=0; ks<7; ++ks){
            size_t i0 = (((size_t)(ocBlk*2+0)*iccTot + icc)*7 + ks)*512 + lane*8;
            size_t i1 = (((size_t)(ocBlk*2+1)*iccTot + icc)*7 + ks)*512 + lane*8;
            bf16x8 a0h = *(const bf16x8*)&wHi[i0];
            bf16x8 a0l = *(const bf16x8*)&wLo[i0];
            bf16x8 a1h = *(const bf16x8*)&wHi[i1];
            bf16x8 a1l = *(const bf16x8*)&wLo[i1];
            bf16x8 bh[NT], bl[NT];
            #pragma unroll
            for (int n=0;n<NT;++n){
                int e = eb[n] + offs[ks];
                bh[n] = *(const bf16x8*)&ldsHi[e];
                bl[n] = *(const bf16x8*)&ldsLo[e];
            }
            #pragma unroll
            for (int n=0;n<NT;++n){
                acc[0][n] = __builtin_amdgcn_mfma_f32_16x16x32_bf16(a0h, bh[n], acc[0][n], 0,0,0);
                acc[0][n] = __builtin_amdgcn_mfma_f32_16x16x32_bf16(a0h, bl[n], acc[0][n], 0,0,0);
                acc[0][n] = __builtin_amdgcn_mfma_f32_16x16x32_bf16(a0l, bh[n], acc[0][n], 0,0,0);
                acc[1][n] = __builtin_amdgcn_mfma_f32_16x16x32_bf16(a1h, bh[n], acc[1][n], 0,0,0);
                acc[1][n] = __builtin_amdgcn_mfma_f32_16x16x32_bf16(a1h, bl[n], acc[1][n], 0,0,0);
                acc[1][n] = __builtin_amdgcn_mfma_f32_16x16x32_bf16(a1l, bh[n], acc[1][n], 0,0,0);
            }
        }
        __syncthreads();
    }

    if (MODE == 0){
        bool rside = (ocBlk < 2);
        #pragma unroll
        for (int m=0;m<2;++m){
            int ocBase = ocBlk*32 + m*16 + (lane>>4)*4;
            f32x4 b4 = *(const f32x4*)&bias[ocBase];
            #pragma unroll
            for (int n=0;n<NT;++n){
                int px = (r0 + wave*RW + (n>>1))*32 + (n&1)*16 + (lane&15);
                if (rside){
                    size_t ii = ((size_t)batch*1024 + px)*64 + ocBase;
                    f32x4 h4 = *(const f32x4*)&h32[ii];
                    u16x4 rH, rL;
                    #pragma unroll
                    for (int j=0;j<4;++j){
                        float r = sigmoidf_(acc[m][n][j] + b4[j]);
                        unsigned short hh,ll; bsplit(r*h4[j],hh,ll);
                        rH[j]=hh; rL[j]=ll;
                    }
                    *(u16x4*)&oHi[ii] = rH;
                    *(u16x4*)&oLo[ii] = rL;
                } else {
                    size_t ii = ((size_t)batch*1024 + px)*64 + ocBase - 64;
                    f32x4 z;
                    #pragma unroll
                    for (int j=0;j<4;++j) z[j] = sigmoidf_(acc[m][n][j] + b4[j]);
                    *(f32x4*)&z32out[ii] = z;
                }
            }
        }
    } else {
        #pragma unroll
        for (int m=0;m<2;++m){
            int oc = ocBlk*32 + m*16 + (lane>>4)*4;
            f32x4 b4 = *(const f32x4*)&bias[oc];
            #pragma unroll
            for (int n=0;n<NT;++n){
                int px = (r0 + wave*RW + (n>>1))*32 + (n&1)*16 + (lane&15);
                size_t ii = ((size_t)batch*1024 + px)*64 + oc;
                f32x4 h4 = *(const f32x4*)&h32[ii];
                f32x4 z4 = *(const f32x4*)&z32in[ii];
                f32x4 hn; u16x4 hh4, hl4;
                #pragma unroll
                for (int j=0;j<4;++j){
                    float c = tanhf(acc[m][n][j] + b4[j]);
                    hn[j] = (1.f - z4[j])*h4[j] + z4[j]*c;
                    unsigned short hh,ll; bsplit(hn[j],hh,ll);
                    hh4[j]=hh; hl4[j]=ll;
                }
                *(f32x4*)&h32out[ii] = hn;
                *(u16x4*)&oHi[ii] = hh4;
                *(u16x4*)&oLo[ii] = hl4;
                if (hsHi){
                    *(u16x4*)&hsHi[ii] = hh4;
                    *(u16x4*)&hsLo[ii] = hl4;
                }
            }
        }
    }
}

// ---------------------------------------------------------------------------
// k_deconv1m: hs (tb,1024px,64ic bf16 hi/lo) -> y1 (tb,32,64,64) fp32,
// k4 lhs_dil2 pad2 as 4 parity-class 2x2 convs via split-bf16 MFMA.
// grid (4 rowtiles, Ntb*4), block 256 (4 waves). 32oc x 8rows x 32cols (parity grid).
// ---------------------------------------------------------------------------
__global__ __launch_bounds__(256) void k_deconv1m(
    const unsigned short* __restrict__ hsHi, const unsigned short* __restrict__ hsLo,
    const unsigned short* __restrict__ wHi, const unsigned short* __restrict__ wLo,
    const float* __restrict__ Bb, float* __restrict__ y1)
{
    __shared__ __align__(16) unsigned short ldsHi[340*8];
    __shared__ __align__(16) unsigned short ldsLo[340*8];
    int tid = threadIdx.x;
    int lane = tid & 63, wave = tid >> 6;
    int r0 = blockIdx.x*8;
    int zb = blockIdx.y; int tbl = zb >> 2; int par = zb & 3;
    int py = par >> 1, px = par & 1;
    const unsigned short* sH = hsHi + (size_t)tbl*65536;
    const unsigned short* sL = hsLo + (size_t)tbl*65536;

    int offs0 = ((lane>>5)*34 + ((lane>>4)&1))*8;
    int eb[4];
    #pragma unroll
    for (int n=0;n<4;++n)
        eb[n] = (((wave*2 + (n>>1)) + py)*34 + (n&1)*16 + (lane&15) + px)*8;

    f32x4 acc[2][4];
    #pragma unroll
    for (int m=0;m<2;++m)
      #pragma unroll
      for (int n=0;n<4;++n) acc[m][n] = (f32x4){0.f,0.f,0.f,0.f};

    for (int icc=0; icc<8; ++icc){
        #pragma unroll
        for (int s0=0; s0<2; ++s0){
            int s = tid + s0*256;
            if (s < 340){
                int ly = s/34, lx = s - ly*34;
                int gy = r0 - 1 + ly, gx = lx - 1;
                u16x8 vh = (u16x8)0, vl = (u16x8)0;
                if (gy>=0 && gy<32 && gx>=0 && gx<32){
                    size_t off = ((size_t)(gy*32+gx))*64 + icc*8;
                    vh = *(const u16x8*)&sH[off];
                    vl = *(const u16x8*)&sL[off];
                }
                *(u16x8*)&ldsHi[s*8] = vh;
                *(u16x8*)&ldsLo[s*8] = vl;
            }
        }
        __syncthreads();
        size_t i0 = ((size_t)((0*4 + par)*8 + icc))*512 + lane*8;
        size_t i1 = ((size_t)((1*4 + par)*8 + icc))*512 + lane*8;
        bf16x8 a0h = *(const bf16x8*)&wHi[i0];
        bf16x8 a0l = *(const bf16x8*)&wLo[i0];
        bf16x8 a1h = *(const bf16x8*)&wHi[i1];
        bf16x8 a1l = *(const bf16x8*)&wLo[i1];
        bf16x8 bh[4], bl[4];
        #pragma unroll
        for (int n=0;n<4;++n){
            int e = eb[n] + offs0;
            bh[n] = *(const bf16x8*)&ldsHi[e];
            bl[n] = *(const bf16x8*)&ldsLo[e];
        }
        #pragma unroll
        for (int n=0;n<4;++n){
            acc[0][n] = __builtin_amdgcn_mfma_f32_16x16x32_bf16(a0h, bh[n], acc[0][n], 0,0,0);
            acc[0][n] = __builtin_amdgcn_mfma_f32_16x16x32_bf16(a0h, bl[n], acc[0][n], 0,0,0);
            acc[0][n] = __builtin_amdgcn_mfma_f32_16x16x32_bf16(a0l, bh[n], acc[0][n], 0,0,0);
            acc[1][n] = __builtin_amdgcn_mfma_f32_16x16x32_bf16(a1h, bh[n], acc[1][n], 0,0,0);
            acc[1][n] = __builtin_amdgcn_mfma_f32_16x16x32_bf16(a1h, bl[n], acc[1][n], 0,0,0);
            acc[1][n] = __builtin_amdgcn_mfma_f32_16x16x32_bf16(a1l, bh[n], acc[1][n], 0,0,0);
        }
        __syncthreads();
    }
    #pragma unroll
    for (int m=0;m<2;++m){
        int ocb = m*16 + (lane>>4)*4;
        #pragma unroll
        for (int n=0;n<4;++n){
            int oyr = r0 + wave*2 + (n>>1);
            int oxc = (n&1)*16 + (lane&15);
            int oy = 2*oyr + py, ox = 2*oxc + px;
            float* dst = y1 + ((size_t)tbl*32 + ocb)*4096 + oy*64 + ox;
            #pragma unroll
            for (int j=0;j<4;++j){
                float v = acc[m][n][j] + Bb[ocb+j];
                dst[(size_t)j*4096] = LRELU(v);
            }
        }
    }
}

// ---------------------------------------------------------------------------
// deconv2: y1 (Ntb,32,64,64) -> out with (t,b) permute, k4 lhs_dil2 pad2, bias.
// ---------------------------------------------------------------------------
__global__ __launch_bounds__(256) void k_deconv2(const float* __restrict__ in,
    const float* __restrict__ W, const float* __restrict__ Bb, float* __restrict__ out,
    int tbOff)
{
    __shared__ float wl[512];
    int tid = threadIdx.x;
    for (int e=tid; e<512; e+=256) wl[e] = W[e];   // [ic][kh][kw], oc=1
    __syncthreads();
    int tbl = blockIdx.y;
    int tb = tbOff + tbl; int t = tb >> 5; int b = tb & 31;
    int idx4 = blockIdx.x*256 + tid;
    int oy = idx4 >> 5; int ox0 = (idx4 & 31)*4;
    int ph = oy & 1;
    const float* base = in + (size_t)tbl*131072;
    float acc0=0.f, acc1=0.f, acc2=0.f, acc3=0.f;
    int ix0 = ox0/2 - 1;
    for (int ic=0; ic<32; ++ic){
        const float* cp = base + ic*4096;
        #pragma unroll
        for (int kk=0; kk<2; ++kk){
            int kh = ph + 2*kk;
            int iy = (oy + kh - 2) >> 1;
            if (iy < 0 || iy > 63) continue;
            const float* rp = cp + (size_t)iy*64;
            float wv0 = (ix0 >= 0)   ? rp[ix0]   : 0.f;
            float wv1 = rp[ix0+1];
            float wv2 = rp[ix0+2];
            float wv3 = (ix0+3 <= 63) ? rp[ix0+3] : 0.f;
            float w0 = wl[ic*16 + kh*4 + 0];
            float w1 = wl[ic*16 + kh*4 + 1];
            float w2 = wl[ic*16 + kh*4 + 2];
            float w3 = wl[ic*16 + kh*4 + 3];
            acc0 += w0*wv0 + w2*wv1;        // p=0: kw 0,2
            acc2 += w0*wv1 + w2*wv2;        // p=2
            acc1 += w1*wv1 + w3*wv2;        // p=1: kw 1,3
            acc3 += w1*wv2 + w3*wv3;        // p=3
        }
    }
    float bv = Bb[0];
    float4 res = make_float4(acc0+bv, acc1+bv, acc2+bv, acc3+bv);
    float* op = out + ((size_t)(b*10 + t))*16384 + (size_t)oy*128 + ox0;
    *(float4*)op = res;
}

// ---------------------------------------------------------------------------
// Workspace (bytes), peak 121,700,352:
//  [0        , 41943040): e2hi [320][1024][64] bf16  / hsHi overlay (decoder)
//  [41943040 , 83886080): e2lo                       / hsLo overlay
//  [83886080 , 92274688): h32  [32][1024][64] fp32
//  [92274688 , 96468992): hHi   [96468992,100663296): hLo
//  [100663296,104857600): rhHi  [104857600,109051904): rhLo
//  [109051904,117440512): z32
//  [117440512,121700352): weight packs (Azr,Ac,Dzr,Dc,D1 x hi/lo)
//  Phase 1: e1c overlay [83886080,125829120) — packs written AFTER phase 1.
//  Phase 4: y1c (64 tb = 33554432 B) overlay [83886080,117440512).
// ---------------------------------------------------------------------------
extern "C" void kernel_launch(void* const* d_in, const int* in_sizes, int n_in,
                              void* d_out, int out_size, void* d_ws, size_t ws_size,
                              hipStream_t stream)
{
    const float* x    = (const float*)d_in[0];
    const float* ew1  = (const float*)d_in[1];
    const float* eb1  = (const float*)d_in[2];
    const float* ew2  = (const float*)d_in[3];
    const float* eb2  = (const float*)d_in[4];
    const float* ewzr = (const float*)d_in[5];
    const float* ebzr = (const float*)d_in[6];
    const float* ewc  = (const float*)d_in[7];
    const float* ebc  = (const float*)d_in[8];
    const float* dwzr = (const float*)d_in[9];
    const float* dbzr = (const float*)d_in[10];
    const float* dwc  = (const float*)d_in[11];
    const float* dbc  = (const float*)d_in[12];
    const float* dw1  = (const float*)d_in[13];
    const float* db1  = (const float*)d_in[14];
    const float* dw2  = (const float*)d_in[15];
    const float* db2  = (const float*)d_in[16];
    float* out = (float*)d_out;
    char* ws = (char*)d_ws;

    unsigned short* e2hi = (unsigned short*)(ws + 0);
    unsigned short* e2lo = (unsigned short*)(ws + 41943040UL);
    float*          h32  = (float*)(ws + 83886080UL);
    unsigned short* hHi  = (unsigned short*)(ws + 92274688UL);
    unsigned short* hLo  = (unsigned short*)(ws + 96468992UL);
    unsigned short* rhHi = (unsigned short*)(ws + 100663296UL);
    unsigned short* rhLo = (unsigned short*)(ws + 104857600UL);
    float*          z32  = (float*)(ws + 109051904UL);
    unsigned short* A0   = (unsigned short*)(ws + 117440512UL);
    unsigned short* AzrH = A0;            unsigned short* AzrL = A0 + 458752;
    unsigned short* AcH  = A0 + 917504;   unsigned short* AcL  = A0 + 1146880;
    unsigned short* DzrH = A0 + 1376256;  unsigned short* DzrL = A0 + 1605632;
    unsigned short* DcH  = A0 + 1835008;  unsigned short* DcL  = A0 + 1949696;
    unsigned short* D1H  = A0 + 2064384;  unsigned short* D1L  = A0 + 2097152;
    float* e1c = (float*)(ws + 83886080UL);   // phase-1 overlay (40 MB)
    float* y1c = (float*)(ws + 83886080UL);   // phase-4 overlay (33.5 MB)

    // Phase 1: conv1 -> conv2 (e2 split channel-last), chunked x2
    for (int c=0; c<2; ++c){
        int off = c*160;
        k_conv1<<<dim3(16,160),256,0,stream>>>(x + (size_t)off*16384, ew1, eb1, e1c);
        k_conv2<<<dim3(4,160),256,0,stream>>>(e1c, ew2, eb2,
                                              e2hi + (size_t)off*65536,
                                              e2lo + (size_t)off*65536);
    }

    // Weight packing AFTER phase 1 (e1c overlay covers the pack region)
    k_prep<<<224,256,0,stream>>>(ewzr, 128, 0, 128, 57344, AzrH, AzrL);
    k_prep<<<112,256,0,stream>>>(ewc,  128, 0, 128, 28672, AcH,  AcL);
    k_prep<<<112,256,0,stream>>>(dwzr, 128, 64, 64, 28672, DzrH, DzrL);
    k_prep<<< 56,256,0,stream>>>(dwc,  128, 64, 64, 14336, DcH,  DcL);
    k_prep_d1<<<16,256,0,stream>>>(dw1, D1H, D1L);

    hipMemsetAsync(h32, 0, 8388608UL, stream);
    hipMemsetAsync(hHi, 0, 4194304UL, stream);
    hipMemsetAsync(hLo, 0, 4194304UL, stream);

    // Phase 2: encoder GRU scan (2 dispatches per step, fused pointwise)
    for (int t=0; t<10; ++t){
        k_conv5f<0,8><<<dim3(4,4,32),256,0,stream>>>(
            e2hi + (size_t)t*65536, e2lo + (size_t)t*65536, 655360ULL, 8,
            hHi, hLo, 65536ULL, AzrH, AzrL, 16, ebzr,
            h32, nullptr, z32, rhHi, rhLo, nullptr, nullptr, nullptr);
        k_conv5f<1,4><<<dim3(2,8,32),256,0,stream>>>(
            e2hi + (size_t)t*65536, e2lo + (size_t)t*65536, 655360ULL, 8,
            rhHi, rhLo, 65536ULL, AcH, AcL, 16, ebc,
            h32, z32, nullptr, hHi, hLo, h32, nullptr, nullptr);
    }
    // Phase 3: decoder GRU scan; hs (bf16 hi/lo) overlays e2
    for (int t=0; t<10; ++t){
        k_conv5f<0,8><<<dim3(4,4,32),256,0,stream>>>(
            hHi, hLo, 65536ULL, 8,
            hHi, hLo, 65536ULL, DzrH, DzrL, 8, dbzr,
            h32, nullptr, z32, rhHi, rhLo, nullptr, nullptr, nullptr);
        k_conv5f<1,4><<<dim3(2,8,32),256,0,stream>>>(
            rhHi, rhLo, 65536ULL, 8,
            rhHi, rhLo, 65536ULL, DcH, DcL, 8, dbc,
            h32, z32, nullptr, hHi, hLo, h32,
            e2hi + (size_t)t*2097152, e2lo + (size_t)t*2097152);
    }
    // Phase 4: deconv1m (MFMA) -> deconv2, chunked x5 over tb (64 each)
    for (int c=0; c<5; ++c){
        int tbOff = c*64;
        k_deconv1m<<<dim3(4,256),256,0,stream>>>(
            e2hi + (size_t)tbOff*65536, e2lo + (size_t)tbOff*65536,
            D1H, D1L, db1, y1c);
        k_deconv2<<<dim3(16,64),256,0,stream>>>(y1c, dw2, db2, out, tbOff);
    }
}

// Round 6
// 3640.091 us; speedup vs baseline: 2.9295x; 1.2447x over previous
//
#include <hip/hip_runtime.h>
#include <math.h>

#define LRELU(v) ((v) >= 0.f ? (v) : 0.2f*(v))

__device__ __forceinline__ float sigmoidf_(float x){ return 1.f/(1.f + expf(-x)); }

typedef __attribute__((ext_vector_type(8))) short bf16x8;
typedef __attribute__((ext_vector_type(4))) float f32x4;
typedef __attribute__((ext_vector_type(8))) unsigned short u16x8;
typedef __attribute__((ext_vector_type(4))) unsigned short u16x4;

__device__ __forceinline__ unsigned short bf16_rne(float x){
    union { float f; unsigned u; } v; v.f = x;
    unsigned r = v.u + 0x7fffu + ((v.u >> 16) & 1u);
    return (unsigned short)(r >> 16);
}
__device__ __forceinline__ float bf16_tof(unsigned short h){
    union { float f; unsigned u; } v; v.u = ((unsigned)h) << 16; return v.f;
}
__device__ __forceinline__ void bsplit(float x, unsigned short& hi, unsigned short& lo){
    hi = bf16_rne(x);
    lo = bf16_rne(x - bf16_tof(hi));
}

// ---------------------------------------------------------------------------
// conv1: x (Nimg,1,128,128) -> e1 (Nimg,16,64,64) fp32 ch-first, k3 s2 p1.
// ---------------------------------------------------------------------------
__global__ __launch_bounds__(256) void k_conv1(const float* __restrict__ x,
    const float* __restrict__ W, const float* __restrict__ Bb, float* __restrict__ out)
{
    __shared__ float wl[144];
    __shared__ float bl[16];
    int tid = threadIdx.x;
    if (tid < 144) { int oc = tid/9, tap = tid%9; wl[tap*16+oc] = W[oc*9+tap]; }
    if (tid < 16) bl[tid] = Bb[tid];
    __syncthreads();
    int img = blockIdx.y;
    int px = blockIdx.x*256 + tid;
    int oy = px >> 6, ox = px & 63;
    const float* xin = x + (size_t)img*16384;
    float acc[16];
    #pragma unroll
    for (int o=0;o<16;++o) acc[o]=bl[o];
    #pragma unroll
    for (int kh=0; kh<3; ++kh){
        int iy = 2*oy + kh - 1;
        bool vy = (iy>=0 && iy<128);
        #pragma unroll
        for (int kw=0; kw<3; ++kw){
            int ix = 2*ox + kw - 1;
            float v = (vy && ix>=0 && ix<128) ? xin[iy*128+ix] : 0.f;
            int tap = kh*3+kw;
            #pragma unroll
            for (int o=0;o<16;++o) acc[o] += wl[tap*16+o]*v;
        }
    }
    float* op = out + (size_t)img*65536 + px;
    #pragma unroll
    for (int o=0;o<16;++o){ float v = acc[o]; op[o*4096] = LRELU(v); }
}

// ---------------------------------------------------------------------------
// conv2: e1 (Nimg,16,64,64) -> e2 split bf16 hi/lo CHANNEL-LAST [img][1024][64]
// ---------------------------------------------------------------------------
__global__ __launch_bounds__(256) void k_conv2(const float* __restrict__ in,
    const float* __restrict__ W, const float* __restrict__ Bb,
    unsigned short* __restrict__ e2hi, unsigned short* __restrict__ e2lo)
{
    __shared__ float tile[2*65*68];
    __shared__ float wl[2*9*16];
    int tid = threadIdx.x;
    int img = blockIdx.y;
    int ocBase = blockIdx.x*16;
    int y = tid >> 3, xg = tid & 7, x0 = xg*4;
    float acc[16][4];
    #pragma unroll
    for (int o=0;o<16;++o){ float b = Bb[ocBase+o];
        #pragma unroll
        for (int p=0;p<4;++p) acc[o][p] = b; }
    const float* base = in + (size_t)img*65536;
    for (int icB=0; icB<16; icB+=2){
        for (int e=tid; e<2210; e+=256){            // 2*65*17 float4
            int c4 = e % 17; int rr = (e/17)%65; int ch = e/(17*65);
            int iy = rr - 1; int ixb = c4*4 - 4;
            float4 v = make_float4(0.f,0.f,0.f,0.f);
            if (iy>=0 && iy<64 && c4>=1)
                v = *(const float4*)(base + (icB+ch)*4096 + iy*64 + ixb);
            *(float4*)(&tile[ch*4420 + rr*68 + c4*4]) = v;
        }
        for (int e=tid; e<288; e+=256){
            int oc = e & 15; int rest = e >> 4; int tap = rest % 9; int ch = rest/9;
            wl[(ch*9+tap)*16 + oc] = W[((ocBase+oc)*16 + icB+ch)*9 + tap];
        }
        __syncthreads();
        #pragma unroll
        for (int ch=0; ch<2; ++ch){
            #pragma unroll
            for (int kh=0; kh<3; ++kh){
                int r = 2*y + kh;
                const float4* row = (const float4*)(&tile[ch*4420 + r*68 + 2*x0]);
                float4 a0=row[0], a1=row[1], a2=row[2];
                float win[12] = {a0.x,a0.y,a0.z,a0.w,a1.x,a1.y,a1.z,a1.w,a2.x,a2.y,a2.z,a2.w};
                #pragma unroll
                for (int kw=0; kw<3; ++kw){
                    const float4* wp = (const float4*)(&wl[(ch*9+kh*3+kw)*16]);
                    float4 w0=wp[0], w1=wp[1], w2=wp[2], w3=wp[3];
                    float wv[16] = {w0.x,w0.y,w0.z,w0.w,w1.x,w1.y,w1.z,w1.w,
                                    w2.x,w2.y,w2.z,w2.w,w3.x,w3.y,w3.z,w3.w};
                    #pragma unroll
                    for (int p=0;p<4;++p){
                        float v = win[2*p + kw + 3];
                        #pragma unroll
                        for (int o=0;o<16;++o) acc[o][p] += wv[o]*v;
                    }
                }
            }
        }
        __syncthreads();
    }
    size_t pxbase = (size_t)img*1024 + y*32 + x0;
    #pragma unroll
    for (int p=0;p<4;++p){
        u16x8 h0v, h1v, l0v, l1v;
        #pragma unroll
        for (int o=0;o<8;++o){
            float v0 = acc[o][p];   v0 = LRELU(v0);
            float v1 = acc[o+8][p]; v1 = LRELU(v1);
            unsigned short hh, ll;
            bsplit(v0,hh,ll); h0v[o]=hh; l0v[o]=ll;
            bsplit(v1,hh,ll); h1v[o]=hh; l1v[o]=ll;
        }
        size_t bo = (pxbase + p)*64 + ocBase;
        *(u16x8*)&e2hi[bo]   = h0v; *(u16x8*)&e2hi[bo+8] = h1v;
        *(u16x8*)&e2lo[bo]   = l0v; *(u16x8*)&e2lo[bo+8] = l1v;
    }
}

// ---------------------------------------------------------------------------
// k_prep: pack conv5 weights into MFMA A-fragment order, bf16 hi/lo.
// ---------------------------------------------------------------------------
__global__ __launch_bounds__(256) void k_prep(const float* __restrict__ W,
    int wIcTot, int wIcOff, int icTot, int total,
    unsigned short* __restrict__ outHi, unsigned short* __restrict__ outLo)
{
    int id = blockIdx.x*256 + threadIdx.x;
    if (id >= total) return;
    int lane = id & 63;
    int grp  = id >> 6;
    int ks = grp % 7;
    int rest = grp / 7;
    int iccTot = icTot >> 3;
    int oc = (rest / iccTot)*16 + (lane & 15);
    int t  = ks*4 + (lane >> 4);
    int icBase = (rest % iccTot)*8;
    u16x8 vh, vl;
    #pragma unroll
    for (int r=0;r<8;++r){
        float v = 0.f;
        if (t < 25) v = W[((size_t)oc*wIcTot + wIcOff + icBase + r)*25 + t];
        unsigned short hh, ll; bsplit(v, hh, ll);
        vh[r]=hh; vl[r]=ll;
    }
    size_t base = ((size_t)grp)*512 + lane*8;
    *(u16x8*)&outHi[base] = vh;
    *(u16x8*)&outLo[base] = vl;
}

// ---------------------------------------------------------------------------
// k_prep_d1: pack deconv1 (4x4, lhs_dil 2) weights per parity class.
// ---------------------------------------------------------------------------
__global__ __launch_bounds__(256) void k_prep_d1(const float* __restrict__ W,
    unsigned short* __restrict__ outHi, unsigned short* __restrict__ outLo)
{
    int id = blockIdx.x*256 + threadIdx.x;
    if (id >= 4096) return;
    int lane = id & 63;
    int grp = id >> 6;
    int icc = grp & 7; int par = (grp>>3)&3; int mt = grp>>5;
    int py = par>>1, px = par&1;
    int oc = mt*16 + (lane&15);
    int t = lane>>4; int a = t>>1, bb = t&1;
    int kh = 2*a+py, kw = 2*bb+px;
    u16x8 vh, vl;
    #pragma unroll
    for (int r=0;r<8;++r){
        int ic = icc*8 + r;
        float v = W[(((size_t)oc*64 + ic)*4 + kh)*4 + kw];
        unsigned short hh, ll; bsplit(v, hh, ll);
        vh[r]=hh; vl[r]=ll;
    }
    size_t base = ((size_t)grp)*512 + lane*8;
    *(u16x8*)&outHi[base] = vh;
    *(u16x8*)&outLo[base] = vl;
}

// ---------------------------------------------------------------------------
// k_conv5f: 5x5 pad2 s1 over 32x32, split-bf16 MFMA shift-GEMM, fused GRU
// pointwise epilogue. MODE 0 = zr (NOC=4): ocBlk<2 -> r/rh, else z.
// MODE 1 = cand (NOC=2): hn=(1-z)h+z*tanh.
// 1-D grid, XCD-aware decode: XCD m holds ONE ocBlk's weights resident in L2,
// and the NOC oc-blocks sharing an input tile run consecutively on one XCD.
// total blocks = NOC * (32/ROWS) * 32.
// ---------------------------------------------------------------------------
template<int MODE, int ROWS, int NOC>
__global__ __launch_bounds__(256) void k_conv5f(
    const unsigned short* __restrict__ aHi, const unsigned short* __restrict__ aLo,
    unsigned long long strA, int iccA,
    const unsigned short* __restrict__ inbHi, const unsigned short* __restrict__ inbLo,
    unsigned long long strB,
    const unsigned short* __restrict__ wHi, const unsigned short* __restrict__ wLo,
    int iccTot,
    const float* __restrict__ bias,
    const float* __restrict__ h32,
    const float* __restrict__ z32in,
    float* __restrict__ z32out,
    unsigned short* __restrict__ oHi, unsigned short* __restrict__ oLo,
    float* __restrict__ h32out,
    unsigned short* __restrict__ hsHi, unsigned short* __restrict__ hsLo)
{
    constexpr int RW = ROWS/4;          // rows per wave
    constexpr int NT = ROWS/2;          // n-tiles per wave
    constexpr int SPOS = (ROWS+4)*36;
    constexpr int SPAN = (32/ROWS)*4;   // per-XCD (batch,rowtile) span
    __shared__ __align__(16) unsigned short ldsHi[SPOS*8];
    __shared__ __align__(16) unsigned short ldsLo[SPOS*8];
    int tid = threadIdx.x;
    int lane = tid & 63, wave = tid >> 6;
    // XCD-aware bijective decode (T1)
    int bid = blockIdx.x;
    int m = bid & 7;
    int kk = bid >> 3;
    int ocBlk = kk % NOC;
    int g = kk / NOC;
    int idx = m*SPAN + g;
    int batch = idx & 31;
    int r0 = (idx >> 5)*ROWS;

    int offs[7];
    #pragma unroll
    for (int ks=0; ks<7; ++ks){
        int t = ks*4 + (lane>>4);
        int dy = (t<25)? t/5 : 2;
        int dx = (t<25)? t%5 : 2;
        offs[ks] = (dy*36 + dx)*8;
    }
    int eb[NT];
    #pragma unroll
    for (int n=0;n<NT;++n)
        eb[n] = (((wave*RW + (n>>1))*36) + (n&1)*16 + (lane&15))*8;

    f32x4 acc[2][NT];
    #pragma unroll
    for (int mm=0;mm<2;++mm)
      #pragma unroll
      for (int n=0;n<NT;++n) acc[mm][n] = (f32x4){0.f,0.f,0.f,0.f};

    for (int icc = 0; icc < iccTot; ++icc){
        const unsigned short* sH; const unsigned short* sL; int icLoc;
        if (icc < iccA){ sH = aHi + (size_t)batch*strA; sL = aLo + (size_t)batch*strA; icLoc = icc; }
        else           { sH = inbHi + (size_t)batch*strB; sL = inbLo + (size_t)batch*strB; icLoc = icc - iccA; }
        #pragma unroll
        for (int s0=0; s0<2; ++s0){
            int s = tid + s0*256;
            if (s < SPOS){
                int ly = s/36, lx = s - ly*36;
                int gy = r0 - 2 + ly, gx = lx - 2;
                u16x8 vh = (u16x8)0, vl = (u16x8)0;
                if (gy>=0 && gy<32 && gx>=0 && gx<32){
                    size_t off = ((size_t)(gy*32+gx))*64 + icLoc*8;
                    vh = *(const u16x8*)&sH[off];
                    vl = *(const u16x8*)&sL[off];
                }
                *(u16x8*)&ldsHi[s*8] = vh;
                *(u16x8*)&ldsLo[s*8] = vl;
            }
        }
        __syncthreads();
        #pragma unroll
        for (int ks=0; ks<7; ++ks){
            size_t i0 = (((size_t)(ocBlk*2+0)*iccTot + icc)*7 + ks)*512 + lane*8;
            size_t i1 = (((size_t)(ocBlk*2+1)*iccTot + icc)*7 + ks)*512 + lane*8;
            bf16x8 a0h = *(const bf16x8*)&wHi[i0];
            bf16x8 a0l = *(const bf16x8*)&wLo[i0];
            bf16x8 a1h = *(const bf16x8*)&wHi[i1];
            bf16x8 a1l = *(const bf16x8*)&wLo[i1];
            bf16x8 bh[NT], bl[NT];
            #pragma unroll
            for (int n=0;n<NT;++n){
                int e = eb[n] + offs[ks];
                bh[n] = *(const bf16x8*)&ldsHi[e];
                bl[n] = *(const bf16x8*)&ldsLo[e];
            }
            #pragma unroll
            for (int n=0;n<NT;++n){
                acc[0][n] = __builtin_amdgcn_mfma_f32_16x16x32_bf16(a0h, bh[n], acc[0][n], 0,0,0);
                acc[0][n] = __builtin_amdgcn_mfma_f32_16x16x32_bf16(a0h, bl[n], acc[0][n], 0,0,0);
                acc[0][n] = __builtin_amdgcn_mfma_f32_16x16x32_bf16(a0l, bh[n], acc[0][n], 0,0,0);
                acc[1][n] = __builtin_amdgcn_mfma_f32_16x16x32_bf16(a1h, bh[n], acc[1][n], 0,0,0);
                acc[1][n] = __builtin_amdgcn_mfma_f32_16x16x32_bf16(a1h, bl[n], acc[1][n], 0,0,0);
                acc[1][n] = __builtin_amdgcn_mfma_f32_16x16x32_bf16(a1l, bh[n], acc[1][n], 0,0,0);
            }
        }
        __syncthreads();
    }

    if (MODE == 0){
        bool rside = (ocBlk < 2);
        #pragma unroll
        for (int mm=0;mm<2;++mm){
            int ocBase = ocBlk*32 + mm*16 + (lane>>4)*4;
            f32x4 b4 = *(const f32x4*)&bias[ocBase];
            #pragma unroll
            for (int n=0;n<NT;++n){
                int px = (r0 + wave*RW + (n>>1))*32 + (n&1)*16 + (lane&15);
                if (rside){
                    size_t ii = ((size_t)batch*1024 + px)*64 + ocBase;
                    f32x4 h4 = *(const f32x4*)&h32[ii];
                    u16x4 rH, rL;
                    #pragma unroll
                    for (int j=0;j<4;++j){
                        float r = sigmoidf_(acc[mm][n][j] + b4[j]);
                        unsigned short hh,ll; bsplit(r*h4[j],hh,ll);
                        rH[j]=hh; rL[j]=ll;
                    }
                    *(u16x4*)&oHi[ii] = rH;
                    *(u16x4*)&oLo[ii] = rL;
                } else {
                    size_t ii = ((size_t)batch*1024 + px)*64 + ocBase - 64;
                    f32x4 z;
                    #pragma unroll
                    for (int j=0;j<4;++j) z[j] = sigmoidf_(acc[mm][n][j] + b4[j]);
                    *(f32x4*)&z32out[ii] = z;
                }
            }
        }
    } else {
        #pragma unroll
        for (int mm=0;mm<2;++mm){
            int oc = ocBlk*32 + mm*16 + (lane>>4)*4;
            f32x4 b4 = *(const f32x4*)&bias[oc];
            #pragma unroll
            for (int n=0;n<NT;++n){
                int px = (r0 + wave*RW + (n>>1))*32 + (n&1)*16 + (lane&15);
                size_t ii = ((size_t)batch*1024 + px)*64 + oc;
                f32x4 h4 = *(const f32x4*)&h32[ii];
                f32x4 z4 = *(const f32x4*)&z32in[ii];
                f32x4 hn; u16x4 hh4, hl4;
                #pragma unroll
                for (int j=0;j<4;++j){
                    float c = tanhf(acc[mm][n][j] + b4[j]);
                    hn[j] = (1.f - z4[j])*h4[j] + z4[j]*c;
                    unsigned short hh,ll; bsplit(hn[j],hh,ll);
                    hh4[j]=hh; hl4[j]=ll;
                }
                *(f32x4*)&h32out[ii] = hn;
                *(u16x4*)&oHi[ii] = hh4;
                *(u16x4*)&oLo[ii] = hl4;
                if (hsHi){
                    *(u16x4*)&hsHi[ii] = hh4;
                    *(u16x4*)&hsLo[ii] = hl4;
                }
            }
        }
    }
}

// ---------------------------------------------------------------------------
// k_deconv1m: hs (tb,1024px,64ic bf16 hi/lo) -> y1 (tb,32,64,64) fp32,
// k4 lhs_dil2 pad2 as 4 parity-class 2x2 convs via split-bf16 MFMA.
// 1-D grid 1024 blocks, XCD-aware decode: 4 parity blocks of one (tbl,rt)
// tile run consecutively on one XCD (input tile fetched once per XCD).
// ---------------------------------------------------------------------------
__global__ __launch_bounds__(256) void k_deconv1m(
    const unsigned short* __restrict__ hsHi, const unsigned short* __restrict__ hsLo,
    const unsigned short* __restrict__ wHi, const unsigned short* __restrict__ wLo,
    const float* __restrict__ Bb, float* __restrict__ y1)
{
    __shared__ __align__(16) unsigned short ldsHi[340*8];
    __shared__ __align__(16) unsigned short ldsLo[340*8];
    int tid = threadIdx.x;
    int lane = tid & 63, wave = tid >> 6;
    int bid = blockIdx.x;
    int m = bid & 7;
    int kk = bid >> 3;
    int par = kk & 3;
    int g = kk >> 2;
    int idx = m*32 + g;
    int tbl = idx & 63;
    int r0 = (idx >> 6)*8;
    int py = par >> 1, px = par & 1;
    const unsigned short* sH = hsHi + (size_t)tbl*65536;
    const unsigned short* sL = hsLo + (size_t)tbl*65536;

    int offs0 = ((lane>>5)*34 + ((lane>>4)&1))*8;
    int eb[4];
    #pragma unroll
    for (int n=0;n<4;++n)
        eb[n] = (((wave*2 + (n>>1)) + py)*34 + (n&1)*16 + (lane&15) + px)*8;

    f32x4 acc[2][4];
    #pragma unroll
    for (int mm=0;mm<2;++mm)
      #pragma unroll
      for (int n=0;n<4;++n) acc[mm][n] = (f32x4){0.f,0.f,0.f,0.f};

    for (int icc=0; icc<8; ++icc){
        #pragma unroll
        for (int s0=0; s0<2; ++s0){
            int s = tid + s0*256;
            if (s < 340){
                int ly = s/34, lx = s - ly*34;
                int gy = r0 - 1 + ly, gx = lx - 1;
                u16x8 vh = (u16x8)0, vl = (u16x8)0;
                if (gy>=0 && gy<32 && gx>=0 && gx<32){
                    size_t off = ((size_t)(gy*32+gx))*64 + icc*8;
                    vh = *(const u16x8*)&sH[off];
                    vl = *(const u16x8*)&sL[off];
                }
                *(u16x8*)&ldsHi[s*8] = vh;
                *(u16x8*)&ldsLo[s*8] = vl;
            }
        }
        __syncthreads();
        size_t i0 = ((size_t)((0*4 + par)*8 + icc))*512 + lane*8;
        size_t i1 = ((size_t)((1*4 + par)*8 + icc))*512 + lane*8;
        bf16x8 a0h = *(const bf16x8*)&wHi[i0];
        bf16x8 a0l = *(const bf16x8*)&wLo[i0];
        bf16x8 a1h = *(const bf16x8*)&wHi[i1];
        bf16x8 a1l = *(const bf16x8*)&wLo[i1];
        bf16x8 bh[4], bl[4];
        #pragma unroll
        for (int n=0;n<4;++n){
            int e = eb[n] + offs0;
            bh[n] = *(const bf16x8*)&ldsHi[e];
            bl[n] = *(const bf16x8*)&ldsLo[e];
        }
        #pragma unroll
        for (int n=0;n<4;++n){
            acc[0][n] = __builtin_amdgcn_mfma_f32_16x16x32_bf16(a0h, bh[n], acc[0][n], 0,0,0);
            acc[0][n] = __builtin_amdgcn_mfma_f32_16x16x32_bf16(a0h, bl[n], acc[0][n], 0,0,0);
            acc[0][n] = __builtin_amdgcn_mfma_f32_16x16x32_bf16(a0l, bh[n], acc[0][n], 0,0,0);
            acc[1][n] = __builtin_amdgcn_mfma_f32_16x16x32_bf16(a1h, bh[n], acc[1][n], 0,0,0);
            acc[1][n] = __builtin_amdgcn_mfma_f32_16x16x32_bf16(a1h, bl[n], acc[1][n], 0,0,0);
            acc[1][n] = __builtin_amdgcn_mfma_f32_16x16x32_bf16(a1l, bh[n], acc[1][n], 0,0,0);
        }
        __syncthreads();
    }
    #pragma unroll
    for (int mm=0;mm<2;++mm){
        int ocb = mm*16 + (lane>>4)*4;
        #pragma unroll
        for (int n=0;n<4;++n){
            int oyr = r0 + wave*2 + (n>>1);
            int oxc = (n&1)*16 + (lane&15);
            int oy = 2*oyr + py, ox = 2*oxc + px;
            float* dst = y1 + ((size_t)tbl*32 + ocb)*4096 + oy*64 + ox;
            #pragma unroll
            for (int j=0;j<4;++j){
                float v = acc[mm][n][j] + Bb[ocb+j];
                dst[(size_t)j*4096] = LRELU(v);
            }
        }
    }
}

// ---------------------------------------------------------------------------
// deconv2: y1 (Ntb,32,64,64) -> out with (t,b) permute, k4 lhs_dil2 pad2, bias.
// ---------------------------------------------------------------------------
__global__ __launch_bounds__(256) void k_deconv2(const float* __restrict__ in,
    const float* __restrict__ W, const float* __restrict__ Bb, float* __restrict__ out,
    int tbOff)
{
    __shared__ float wl[512];
    int tid = threadIdx.x;
    for (int e=tid; e<512; e+=256) wl[e] = W[e];   // [ic][kh][kw], oc=1
    __syncthreads();
    int tbl = blockIdx.y;
    int tb = tbOff + tbl; int t = tb >> 5; int b = tb & 31;
    int idx4 = blockIdx.x*256 + tid;
    int oy = idx4 >> 5; int ox0 = (idx4 & 31)*4;
    int ph = oy & 1;
    const float* base = in + (size_t)tbl*131072;
    float acc0=0.f, acc1=0.f, acc2=0.f, acc3=0.f;
    int ix0 = ox0/2 - 1;
    for (int ic=0; ic<32; ++ic){
        const float* cp = base + ic*4096;
        #pragma unroll
        for (int kk=0; kk<2; ++kk){
            int kh = ph + 2*kk;
            int iy = (oy + kh - 2) >> 1;
            if (iy < 0 || iy > 63) continue;
            const float* rp = cp + (size_t)iy*64;
            float wv0 = (ix0 >= 0)   ? rp[ix0]   : 0.f;
            float wv1 = rp[ix0+1];
            float wv2 = rp[ix0+2];
            float wv3 = (ix0+3 <= 63) ? rp[ix0+3] : 0.f;
            float w0 = wl[ic*16 + kh*4 + 0];
            float w1 = wl[ic*16 + kh*4 + 1];
            float w2 = wl[ic*16 + kh*4 + 2];
            float w3 = wl[ic*16 + kh*4 + 3];
            acc0 += w0*wv0 + w2*wv1;        // p=0: kw 0,2
            acc2 += w0*wv1 + w2*wv2;        // p=2
            acc1 += w1*wv1 + w3*wv2;        // p=1: kw 1,3
            acc3 += w1*wv2 + w3*wv3;        // p=3
        }
    }
    float bv = Bb[0];
    float4 res = make_float4(acc0+bv, acc1+bv, acc2+bv, acc3+bv);
    float* op = out + ((size_t)(b*10 + t))*16384 + (size_t)oy*128 + ox0;
    *(float4*)op = res;
}

// ---------------------------------------------------------------------------
// Workspace (bytes), peak 121,700,352 — layout identical to round 5.
// ---------------------------------------------------------------------------
extern "C" void kernel_launch(void* const* d_in, const int* in_sizes, int n_in,
                              void* d_out, int out_size, void* d_ws, size_t ws_size,
                              hipStream_t stream)
{
    const float* x    = (const float*)d_in[0];
    const float* ew1  = (const float*)d_in[1];
    const float* eb1  = (const float*)d_in[2];
    const float* ew2  = (const float*)d_in[3];
    const float* eb2  = (const float*)d_in[4];
    const float* ewzr = (const float*)d_in[5];
    const float* ebzr = (const float*)d_in[6];
    const float* ewc  = (const float*)d_in[7];
    const float* ebc  = (const float*)d_in[8];
    const float* dwzr = (const float*)d_in[9];
    const float* dbzr = (const float*)d_in[10];
    const float* dwc  = (const float*)d_in[11];
    const float* dbc  = (const float*)d_in[12];
    const float* dw1  = (const float*)d_in[13];
    const float* db1  = (const float*)d_in[14];
    const float* dw2  = (const float*)d_in[15];
    const float* db2  = (const float*)d_in[16];
    float* out = (float*)d_out;
    char* ws = (char*)d_ws;

    unsigned short* e2hi = (unsigned short*)(ws + 0);
    unsigned short* e2lo = (unsigned short*)(ws + 41943040UL);
    float*          h32  = (float*)(ws + 83886080UL);
    unsigned short* hHi  = (unsigned short*)(ws + 92274688UL);
    unsigned short* hLo  = (unsigned short*)(ws + 96468992UL);
    unsigned short* rhHi = (unsigned short*)(ws + 100663296UL);
    unsigned short* rhLo = (unsigned short*)(ws + 104857600UL);
    float*          z32  = (float*)(ws + 109051904UL);
    unsigned short* A0   = (unsigned short*)(ws + 117440512UL);
    unsigned short* AzrH = A0;            unsigned short* AzrL = A0 + 458752;
    unsigned short* AcH  = A0 + 917504;   unsigned short* AcL  = A0 + 1146880;
    unsigned short* DzrH = A0 + 1376256;  unsigned short* DzrL = A0 + 1605632;
    unsigned short* DcH  = A0 + 1835008;  unsigned short* DcL  = A0 + 1949696;
    unsigned short* D1H  = A0 + 2064384;  unsigned short* D1L  = A0 + 2097152;
    float* e1c = (float*)(ws + 83886080UL);   // phase-1 overlay (40 MB)
    float* y1c = (float*)(ws + 83886080UL);   // phase-4 overlay (33.5 MB)

    // Phase 1: conv1 -> conv2 (e2 split channel-last), chunked x2
    for (int c=0; c<2; ++c){
        int off = c*160;
        k_conv1<<<dim3(16,160),256,0,stream>>>(x + (size_t)off*16384, ew1, eb1, e1c);
        k_conv2<<<dim3(4,160),256,0,stream>>>(e1c, ew2, eb2,
                                              e2hi + (size_t)off*65536,
                                              e2lo + (size_t)off*65536);
    }

    // Weight packing AFTER phase 1 (e1c overlay covers the pack region)
    k_prep<<<224,256,0,stream>>>(ewzr, 128, 0, 128, 57344, AzrH, AzrL);
    k_prep<<<112,256,0,stream>>>(ewc,  128, 0, 128, 28672, AcH,  AcL);
    k_prep<<<112,256,0,stream>>>(dwzr, 128, 64, 64, 28672, DzrH, DzrL);
    k_prep<<< 56,256,0,stream>>>(dwc,  128, 64, 64, 14336, DcH,  DcL);
    k_prep_d1<<<16,256,0,stream>>>(dw1, D1H, D1L);

    hipMemsetAsync(h32, 0, 8388608UL, stream);
    hipMemsetAsync(hHi, 0, 4194304UL, stream);
    hipMemsetAsync(hLo, 0, 4194304UL, stream);

    // Phase 2: encoder GRU scan (2 dispatches per step, fused pointwise)
    for (int t=0; t<10; ++t){
        k_conv5f<0,8,4><<<512,256,0,stream>>>(
            e2hi + (size_t)t*65536, e2lo + (size_t)t*65536, 655360ULL, 8,
            hHi, hLo, 65536ULL, AzrH, AzrL, 16, ebzr,
            h32, nullptr, z32, rhHi, rhLo, nullptr, nullptr, nullptr);
        k_conv5f<1,4,2><<<512,256,0,stream>>>(
            e2hi + (size_t)t*65536, e2lo + (size_t)t*65536, 655360ULL, 8,
            rhHi, rhLo, 65536ULL, AcH, AcL, 16, ebc,
            h32, z32, nullptr, hHi, hLo, h32, nullptr, nullptr);
    }
    // Phase 3: decoder GRU scan; hs (bf16 hi/lo) overlays e2
    for (int t=0; t<10; ++t){
        k_conv5f<0,8,4><<<512,256,0,stream>>>(
            hHi, hLo, 65536ULL, 8,
            hHi, hLo, 65536ULL, DzrH, DzrL, 8, dbzr,
            h32, nullptr, z32, rhHi, rhLo, nullptr, nullptr, nullptr);
        k_conv5f<1,4,2><<<512,256,0,stream>>>(
            rhHi, rhLo, 65536ULL, 8,
            rhHi, rhLo, 65536ULL, DcH, DcL, 8, dbc,
            h32, z32, nullptr, hHi, hLo, h32,
            e2hi + (size_t)t*2097152, e2lo + (size_t)t*2097152);
    }
    // Phase 4: deconv1m (MFMA) -> deconv2, chunked x5 over tb (64 each)
    for (int c=0; c<5; ++c){
        int tbOff = c*64;
        k_deconv1m<<<1024,256,0,stream>>>(
            e2hi + (size_t)tbOff*65536, e2lo + (size_t)tbOff*65536,
            D1H, D1L, db1, y1c);
        k_deconv2<<<dim3(16,64),256,0,stream>>>(y1c, dw2, db2, out, tbOff);
    }
}

// Round 7
// 2948.329 us; speedup vs baseline: 3.6169x; 1.2346x over previous
//
#include <hip/hip_runtime.h>
#include <math.h>

#define LRELU(v) ((v) >= 0.f ? (v) : 0.2f*(v))

__device__ __forceinline__ float sigmoidf_(float x){ return 1.f/(1.f + expf(-x)); }

typedef __attribute__((ext_vector_type(8))) short bf16x8;
typedef __attribute__((ext_vector_type(4))) float f32x4;
typedef __attribute__((ext_vector_type(8))) unsigned short u16x8;
typedef __attribute__((ext_vector_type(4))) unsigned short u16x4;

__device__ __forceinline__ unsigned short bf16_rne(float x){
    union { float f; unsigned u; } v; v.f = x;
    unsigned r = v.u + 0x7fffu + ((v.u >> 16) & 1u);
    return (unsigned short)(r >> 16);
}
__device__ __forceinline__ float bf16_tof(unsigned short h){
    union { float f; unsigned u; } v; v.u = ((unsigned)h) << 16; return v.f;
}
__device__ __forceinline__ void bsplit(float x, unsigned short& hi, unsigned short& lo){
    hi = bf16_rne(x);
    lo = bf16_rne(x - bf16_tof(hi));
}

// ---------------------------------------------------------------------------
// conv1: x (Nimg,1,128,128) -> e1 (Nimg,16,64,64) fp32 ch-first, k3 s2 p1.
// ---------------------------------------------------------------------------
__global__ __launch_bounds__(256) void k_conv1(const float* __restrict__ x,
    const float* __restrict__ W, const float* __restrict__ Bb, float* __restrict__ out)
{
    __shared__ float wl[144];
    __shared__ float bl[16];
    int tid = threadIdx.x;
    if (tid < 144) { int oc = tid/9, tap = tid%9; wl[tap*16+oc] = W[oc*9+tap]; }
    if (tid < 16) bl[tid] = Bb[tid];
    __syncthreads();
    int img = blockIdx.y;
    int px = blockIdx.x*256 + tid;
    int oy = px >> 6, ox = px & 63;
    const float* xin = x + (size_t)img*16384;
    float acc[16];
    #pragma unroll
    for (int o=0;o<16;++o) acc[o]=bl[o];
    #pragma unroll
    for (int kh=0; kh<3; ++kh){
        int iy = 2*oy + kh - 1;
        bool vy = (iy>=0 && iy<128);
        #pragma unroll
        for (int kw=0; kw<3; ++kw){
            int ix = 2*ox + kw - 1;
            float v = (vy && ix>=0 && ix<128) ? xin[iy*128+ix] : 0.f;
            int tap = kh*3+kw;
            #pragma unroll
            for (int o=0;o<16;++o) acc[o] += wl[tap*16+o]*v;
        }
    }
    float* op = out + (size_t)img*65536 + px;
    #pragma unroll
    for (int o=0;o<16;++o){ float v = acc[o]; op[o*4096] = LRELU(v); }
}

// ---------------------------------------------------------------------------
// conv2: e1 (Nimg,16,64,64) -> e2 split bf16 hi/lo CHANNEL-LAST [img][1024][64]
// ---------------------------------------------------------------------------
__global__ __launch_bounds__(256) void k_conv2(const float* __restrict__ in,
    const float* __restrict__ W, const float* __restrict__ Bb,
    unsigned short* __restrict__ e2hi, unsigned short* __restrict__ e2lo)
{
    __shared__ float tile[2*65*68];
    __shared__ float wl[2*9*16];
    int tid = threadIdx.x;
    int img = blockIdx.y;
    int ocBase = blockIdx.x*16;
    int y = tid >> 3, xg = tid & 7, x0 = xg*4;
    float acc[16][4];
    #pragma unroll
    for (int o=0;o<16;++o){ float b = Bb[ocBase+o];
        #pragma unroll
        for (int p=0;p<4;++p) acc[o][p] = b; }
    const float* base = in + (size_t)img*65536;
    for (int icB=0; icB<16; icB+=2){
        for (int e=tid; e<2210; e+=256){            // 2*65*17 float4
            int c4 = e % 17; int rr = (e/17)%65; int ch = e/(17*65);
            int iy = rr - 1; int ixb = c4*4 - 4;
            float4 v = make_float4(0.f,0.f,0.f,0.f);
            if (iy>=0 && iy<64 && c4>=1)
                v = *(const float4*)(base + (icB+ch)*4096 + iy*64 + ixb);
            *(float4*)(&tile[ch*4420 + rr*68 + c4*4]) = v;
        }
        for (int e=tid; e<288; e+=256){
            int oc = e & 15; int rest = e >> 4; int tap = rest % 9; int ch = rest/9;
            wl[(ch*9+tap)*16 + oc] = W[((ocBase+oc)*16 + icB+ch)*9 + tap];
        }
        __syncthreads();
        #pragma unroll
        for (int ch=0; ch<2; ++ch){
            #pragma unroll
            for (int kh=0; kh<3; ++kh){
                int r = 2*y + kh;
                const float4* row = (const float4*)(&tile[ch*4420 + r*68 + 2*x0]);
                float4 a0=row[0], a1=row[1], a2=row[2];
                float win[12] = {a0.x,a0.y,a0.z,a0.w,a1.x,a1.y,a1.z,a1.w,a2.x,a2.y,a2.z,a2.w};
                #pragma unroll
                for (int kw=0; kw<3; ++kw){
                    const float4* wp = (const float4*)(&wl[(ch*9+kh*3+kw)*16]);
                    float4 w0=wp[0], w1=wp[1], w2=wp[2], w3=wp[3];
                    float wv[16] = {w0.x,w0.y,w0.z,w0.w,w1.x,w1.y,w1.z,w1.w,
                                    w2.x,w2.y,w2.z,w2.w,w3.x,w3.y,w3.z,w3.w};
                    #pragma unroll
                    for (int p=0;p<4;++p){
                        float v = win[2*p + kw + 3];
                        #pragma unroll
                        for (int o=0;o<16;++o) acc[o][p] += wv[o]*v;
                    }
                }
            }
        }
        __syncthreads();
    }
    size_t pxbase = (size_t)img*1024 + y*32 + x0;
    #pragma unroll
    for (int p=0;p<4;++p){
        u16x8 h0v, h1v, l0v, l1v;
        #pragma unroll
        for (int o=0;o<8;++o){
            float v0 = acc[o][p];   v0 = LRELU(v0);
            float v1 = acc[o+8][p]; v1 = LRELU(v1);
            unsigned short hh, ll;
            bsplit(v0,hh,ll); h0v[o]=hh; l0v[o]=ll;
            bsplit(v1,hh,ll); h1v[o]=hh; l1v[o]=ll;
        }
        size_t bo = (pxbase + p)*64 + ocBase;
        *(u16x8*)&e2hi[bo]   = h0v; *(u16x8*)&e2hi[bo+8] = h1v;
        *(u16x8*)&e2lo[bo]   = l0v; *(u16x8*)&e2lo[bo+8] = l1v;
    }
}

// ---------------------------------------------------------------------------
// k_prep: pack conv5 weights into MFMA A-fragment order, bf16 hi/lo.
// ---------------------------------------------------------------------------
__global__ __launch_bounds__(256) void k_prep(const float* __restrict__ W,
    int wIcTot, int wIcOff, int icTot, int total,
    unsigned short* __restrict__ outHi, unsigned short* __restrict__ outLo)
{
    int id = blockIdx.x*256 + threadIdx.x;
    if (id >= total) return;
    int lane = id & 63;
    int grp  = id >> 6;
    int ks = grp % 7;
    int rest = grp / 7;
    int iccTot = icTot >> 3;
    int oc = (rest / iccTot)*16 + (lane & 15);
    int t  = ks*4 + (lane >> 4);
    int icBase = (rest % iccTot)*8;
    u16x8 vh, vl;
    #pragma unroll
    for (int r=0;r<8;++r){
        float v = 0.f;
        if (t < 25) v = W[((size_t)oc*wIcTot + wIcOff + icBase + r)*25 + t];
        unsigned short hh, ll; bsplit(v, hh, ll);
        vh[r]=hh; vl[r]=ll;
    }
    size_t base = ((size_t)grp)*512 + lane*8;
    *(u16x8*)&outHi[base] = vh;
    *(u16x8*)&outLo[base] = vl;
}

// ---------------------------------------------------------------------------
// k_prep_d1: pack deconv1 (4x4, lhs_dil 2) weights per parity class.
// ---------------------------------------------------------------------------
__global__ __launch_bounds__(256) void k_prep_d1(const float* __restrict__ W,
    unsigned short* __restrict__ outHi, unsigned short* __restrict__ outLo)
{
    int id = blockIdx.x*256 + threadIdx.x;
    if (id >= 4096) return;
    int lane = id & 63;
    int grp = id >> 6;
    int icc = grp & 7; int par = (grp>>3)&3; int mt = grp>>5;
    int py = par>>1, px = par&1;
    int oc = mt*16 + (lane&15);
    int t = lane>>4; int a = t>>1, bb = t&1;
    int kh = 2*a+py, kw = 2*bb+px;
    u16x8 vh, vl;
    #pragma unroll
    for (int r=0;r<8;++r){
        int ic = icc*8 + r;
        float v = W[(((size_t)oc*64 + ic)*4 + kh)*4 + kw];
        unsigned short hh, ll; bsplit(v, hh, ll);
        vh[r]=hh; vl[r]=ll;
    }
    size_t base = ((size_t)grp)*512 + lane*8;
    *(u16x8*)&outHi[base] = vh;
    *(u16x8*)&outLo[base] = vl;
}

// ---------------------------------------------------------------------------
// k_conv5f: 5x5 pad2 s1 over 32x32, split-bf16 MFMA shift-GEMM, fused GRU
// pointwise epilogue. Double-buffered LDS + register prefetch (T14):
// per icc: barrier -> issue next-icc global loads -> MFMA compute (hides
// latency) -> regs->LDS[other buf]. One barrier per iteration.
// MODE 0 = zr (NOC=4): ocBlk<2 -> r/rh, else z. MODE 1 = cand (NOC=2).
// 1-D grid NOC*(32/ROWS)*32, XCD-aware bijective decode (T1): the NOC
// oc-blocks sharing an input tile run consecutively on one XCD.
// ---------------------------------------------------------------------------
template<int MODE, int ROWS, int NOC>
__global__ __launch_bounds__(256) void k_conv5f(
    const unsigned short* __restrict__ aHi, const unsigned short* __restrict__ aLo,
    unsigned long long strA, int iccA,
    const unsigned short* __restrict__ inbHi, const unsigned short* __restrict__ inbLo,
    unsigned long long strB,
    const unsigned short* __restrict__ wHi, const unsigned short* __restrict__ wLo,
    int iccTot,
    const float* __restrict__ bias,
    const float* __restrict__ h32,
    const float* __restrict__ z32in,
    float* __restrict__ z32out,
    unsigned short* __restrict__ oHi, unsigned short* __restrict__ oLo,
    float* __restrict__ h32out,
    unsigned short* __restrict__ hsHi, unsigned short* __restrict__ hsLo)
{
    constexpr int RW = ROWS/4;          // rows per wave
    constexpr int NT = ROWS/2;          // n-tiles per wave
    constexpr int SPOS = (ROWS+4)*36;
    constexpr int SPAN = (32/ROWS)*4;   // per-XCD (batch,rowtile) span
    __shared__ __align__(16) unsigned short ldsHi[2][SPOS*8];
    __shared__ __align__(16) unsigned short ldsLo[2][SPOS*8];
    int tid = threadIdx.x;
    int lane = tid & 63, wave = tid >> 6;
    int bid = blockIdx.x;
    int m = bid & 7;
    int kk = bid >> 3;
    int ocBlk = kk % NOC;
    int g = kk / NOC;
    int idx = m*SPAN + g;
    int batch = idx & 31;
    int r0 = (idx >> 5)*ROWS;

    // staging geometry (icc-invariant)
    int sA = tid;                       // SPOS >= 288 > 255 -> always valid slot
    int lyA = sA/36, lxA = sA - lyA*36;
    int gyA = r0 - 2 + lyA, gxA = lxA - 2;
    bool vA = (gyA>=0 && gyA<32 && gxA>=0 && gxA<32);
    size_t poA = ((size_t)(gyA*32+gxA))*64;
    int sB = tid + 256;
    bool hasB = (sB < SPOS);
    int lyB = sB/36, lxB = sB - lyB*36;
    int gyB = r0 - 2 + lyB, gxB = lxB - 2;
    bool vB = hasB && (gyB>=0 && gyB<32 && gxB>=0 && gxB<32);
    size_t poB = ((size_t)(gyB*32+gxB))*64;

    int offs[7];
    #pragma unroll
    for (int ks=0; ks<7; ++ks){
        int t = ks*4 + (lane>>4);
        int dy = (t<25)? t/5 : 2;
        int dx = (t<25)? t%5 : 2;
        offs[ks] = (dy*36 + dx)*8;
    }
    int eb[NT];
    #pragma unroll
    for (int n=0;n<NT;++n)
        eb[n] = (((wave*RW + (n>>1))*36) + (n&1)*16 + (lane&15))*8;

    f32x4 acc[2][NT];
    #pragma unroll
    for (int mm=0;mm<2;++mm)
      #pragma unroll
      for (int n=0;n<NT;++n) acc[mm][n] = (f32x4){0.f,0.f,0.f,0.f};

    // prefetch registers (named, no dynamic indexing)
    u16x8 rAh=(u16x8)0, rAl=(u16x8)0, rBh=(u16x8)0, rBl=(u16x8)0;

    // ---- LOAD icc=0 into regs
    {
        const unsigned short* sHp; const unsigned short* sLp; int icLoc;
        if (0 < iccA){ sHp = aHi + (size_t)batch*strA; sLp = aLo + (size_t)batch*strA; icLoc = 0; }
        else         { sHp = inbHi + (size_t)batch*strB; sLp = inbLo + (size_t)batch*strB; icLoc = -iccA; }
        if (vA){ rAh = *(const u16x8*)&sHp[poA + icLoc*8]; rAl = *(const u16x8*)&sLp[poA + icLoc*8]; }
        if (vB){ rBh = *(const u16x8*)&sHp[poB + icLoc*8]; rBl = *(const u16x8*)&sLp[poB + icLoc*8]; }
    }
    // ---- STORE buf0
    *(u16x8*)&ldsHi[0][sA*8] = rAh; *(u16x8*)&ldsLo[0][sA*8] = rAl;
    if (hasB){ *(u16x8*)&ldsHi[0][sB*8] = rBh; *(u16x8*)&ldsLo[0][sB*8] = rBl; }

    int cur = 0;
    for (int icc = 0; icc < iccTot; ++icc){
        __syncthreads();                 // buf[cur] writes visible
        // ---- issue next-icc loads (no wait; consumed after compute)
        if (icc+1 < iccTot){
            int icn = icc+1;
            const unsigned short* sHp; const unsigned short* sLp; int icLoc;
            if (icn < iccA){ sHp = aHi + (size_t)batch*strA; sLp = aLo + (size_t)batch*strA; icLoc = icn; }
            else           { sHp = inbHi + (size_t)batch*strB; sLp = inbLo + (size_t)batch*strB; icLoc = icn - iccA; }
            rAh=(u16x8)0; rAl=(u16x8)0; rBh=(u16x8)0; rBl=(u16x8)0;
            if (vA){ rAh = *(const u16x8*)&sHp[poA + icLoc*8]; rAl = *(const u16x8*)&sLp[poA + icLoc*8]; }
            if (vB){ rBh = *(const u16x8*)&sHp[poB + icLoc*8]; rBl = *(const u16x8*)&sLp[poB + icLoc*8]; }
        }
        // ---- compute on buf[cur]
        const unsigned short* bHp = ldsHi[cur];
        const unsigned short* bLp = ldsLo[cur];
        #pragma unroll
        for (int ks=0; ks<7; ++ks){
            size_t i0 = (((size_t)(ocBlk*2+0)*iccTot + icc)*7 + ks)*512 + lane*8;
            size_t i1 = (((size_t)(ocBlk*2+1)*iccTot + icc)*7 + ks)*512 + lane*8;
            bf16x8 a0h = *(const bf16x8*)&wHi[i0];
            bf16x8 a0l = *(const bf16x8*)&wLo[i0];
            bf16x8 a1h = *(const bf16x8*)&wHi[i1];
            bf16x8 a1l = *(const bf16x8*)&wLo[i1];
            bf16x8 bh[NT], bl[NT];
            #pragma unroll
            for (int n=0;n<NT;++n){
                int e = eb[n] + offs[ks];
                bh[n] = *(const bf16x8*)&bHp[e];
                bl[n] = *(const bf16x8*)&bLp[e];
            }
            #pragma unroll
            for (int n=0;n<NT;++n){
                acc[0][n] = __builtin_amdgcn_mfma_f32_16x16x32_bf16(a0h, bh[n], acc[0][n], 0,0,0);
                acc[0][n] = __builtin_amdgcn_mfma_f32_16x16x32_bf16(a0h, bl[n], acc[0][n], 0,0,0);
                acc[0][n] = __builtin_amdgcn_mfma_f32_16x16x32_bf16(a0l, bh[n], acc[0][n], 0,0,0);
                acc[1][n] = __builtin_amdgcn_mfma_f32_16x16x32_bf16(a1h, bh[n], acc[1][n], 0,0,0);
                acc[1][n] = __builtin_amdgcn_mfma_f32_16x16x32_bf16(a1h, bl[n], acc[1][n], 0,0,0);
                acc[1][n] = __builtin_amdgcn_mfma_f32_16x16x32_bf16(a1l, bh[n], acc[1][n], 0,0,0);
            }
        }
        // ---- write prefetched regs to the other buffer
        if (icc+1 < iccTot){
            int nb = cur ^ 1;
            *(u16x8*)&ldsHi[nb][sA*8] = rAh; *(u16x8*)&ldsLo[nb][sA*8] = rAl;
            if (hasB){ *(u16x8*)&ldsHi[nb][sB*8] = rBh; *(u16x8*)&ldsLo[nb][sB*8] = rBl; }
        }
        cur ^= 1;
    }

    if (MODE == 0){
        bool rside = (ocBlk < 2);
        #pragma unroll
        for (int mm=0;mm<2;++mm){
            int ocBase = ocBlk*32 + mm*16 + (lane>>4)*4;
            f32x4 b4 = *(const f32x4*)&bias[ocBase];
            #pragma unroll
            for (int n=0;n<NT;++n){
                int px = (r0 + wave*RW + (n>>1))*32 + (n&1)*16 + (lane&15);
                if (rside){
                    size_t ii = ((size_t)batch*1024 + px)*64 + ocBase;
                    f32x4 h4 = *(const f32x4*)&h32[ii];
                    u16x4 rH, rL;
                    #pragma unroll
                    for (int j=0;j<4;++j){
                        float r = sigmoidf_(acc[mm][n][j] + b4[j]);
                        unsigned short hh,ll; bsplit(r*h4[j],hh,ll);
                        rH[j]=hh; rL[j]=ll;
                    }
                    *(u16x4*)&oHi[ii] = rH;
                    *(u16x4*)&oLo[ii] = rL;
                } else {
                    size_t ii = ((size_t)batch*1024 + px)*64 + ocBase - 64;
                    f32x4 z;
                    #pragma unroll
                    for (int j=0;j<4;++j) z[j] = sigmoidf_(acc[mm][n][j] + b4[j]);
                    *(f32x4*)&z32out[ii] = z;
                }
            }
        }
    } else {
        #pragma unroll
        for (int mm=0;mm<2;++mm){
            int oc = ocBlk*32 + mm*16 + (lane>>4)*4;
            f32x4 b4 = *(const f32x4*)&bias[oc];
            #pragma unroll
            for (int n=0;n<NT;++n){
                int px = (r0 + wave*RW + (n>>1))*32 + (n&1)*16 + (lane&15);
                size_t ii = ((size_t)batch*1024 + px)*64 + oc;
                f32x4 h4 = *(const f32x4*)&h32[ii];
                f32x4 z4 = *(const f32x4*)&z32in[ii];
                f32x4 hn; u16x4 hh4, hl4;
                #pragma unroll
                for (int j=0;j<4;++j){
                    float c = tanhf(acc[mm][n][j] + b4[j]);
                    hn[j] = (1.f - z4[j])*h4[j] + z4[j]*c;
                    unsigned short hh,ll; bsplit(hn[j],hh,ll);
                    hh4[j]=hh; hl4[j]=ll;
                }
                *(f32x4*)&h32out[ii] = hn;
                *(u16x4*)&oHi[ii] = hh4;
                *(u16x4*)&oLo[ii] = hl4;
                if (hsHi){
                    *(u16x4*)&hsHi[ii] = hh4;
                    *(u16x4*)&hsLo[ii] = hl4;
                }
            }
        }
    }
}

// ---------------------------------------------------------------------------
// k_deconv1m: hs (tb,1024px,64ic bf16 hi/lo) -> y1 (tb,32,64,64) fp32,
// k4 lhs_dil2 pad2 as 4 parity-class 2x2 convs via split-bf16 MFMA.
// Double-buffered staging (T14), XCD-aware decode (T1).
// ---------------------------------------------------------------------------
__global__ __launch_bounds__(256) void k_deconv1m(
    const unsigned short* __restrict__ hsHi, const unsigned short* __restrict__ hsLo,
    const unsigned short* __restrict__ wHi, const unsigned short* __restrict__ wLo,
    const float* __restrict__ Bb, float* __restrict__ y1)
{
    __shared__ __align__(16) unsigned short ldsHi[2][340*8];
    __shared__ __align__(16) unsigned short ldsLo[2][340*8];
    int tid = threadIdx.x;
    int lane = tid & 63, wave = tid >> 6;
    int bid = blockIdx.x;
    int m = bid & 7;
    int kk = bid >> 3;
    int par = kk & 3;
    int g = kk >> 2;
    int idx = m*32 + g;
    int tbl = idx & 63;
    int r0 = (idx >> 6)*8;
    int py = par >> 1, px = par & 1;
    const unsigned short* sH = hsHi + (size_t)tbl*65536;
    const unsigned short* sL = hsLo + (size_t)tbl*65536;

    // staging geometry
    int sA = tid;
    int lyA = sA/34, lxA = sA - lyA*34;
    int gyA = r0 - 1 + lyA, gxA = lxA - 1;
    bool vA = (gyA>=0 && gyA<32 && gxA>=0 && gxA<32);
    size_t poA = ((size_t)(gyA*32+gxA))*64;
    int sB = tid + 256;
    bool hasB = (sB < 340);
    int lyB = sB/34, lxB = sB - lyB*34;
    int gyB = r0 - 1 + lyB, gxB = lxB - 1;
    bool vB = hasB && (gyB>=0 && gyB<32 && gxB>=0 && gxB<32);
    size_t poB = ((size_t)(gyB*32+gxB))*64;

    int offs0 = ((lane>>5)*34 + ((lane>>4)&1))*8;
    int eb[4];
    #pragma unroll
    for (int n=0;n<4;++n)
        eb[n] = (((wave*2 + (n>>1)) + py)*34 + (n&1)*16 + (lane&15) + px)*8;

    f32x4 acc[2][4];
    #pragma unroll
    for (int mm=0;mm<2;++mm)
      #pragma unroll
      for (int n=0;n<4;++n) acc[mm][n] = (f32x4){0.f,0.f,0.f,0.f};

    u16x8 rAh=(u16x8)0, rAl=(u16x8)0, rBh=(u16x8)0, rBl=(u16x8)0;
    if (vA){ rAh = *(const u16x8*)&sH[poA]; rAl = *(const u16x8*)&sL[poA]; }
    if (vB){ rBh = *(const u16x8*)&sH[poB]; rBl = *(const u16x8*)&sL[poB]; }
    *(u16x8*)&ldsHi[0][sA*8] = rAh; *(u16x8*)&ldsLo[0][sA*8] = rAl;
    if (hasB){ *(u16x8*)&ldsHi[0][sB*8] = rBh; *(u16x8*)&ldsLo[0][sB*8] = rBl; }

    int cur = 0;
    for (int icc=0; icc<8; ++icc){
        __syncthreads();
        if (icc+1 < 8){
            size_t co = (size_t)(icc+1)*8;
            rAh=(u16x8)0; rAl=(u16x8)0; rBh=(u16x8)0; rBl=(u16x8)0;
            if (vA){ rAh = *(const u16x8*)&sH[poA + co]; rAl = *(const u16x8*)&sL[poA + co]; }
            if (vB){ rBh = *(const u16x8*)&sH[poB + co]; rBl = *(const u16x8*)&sL[poB + co]; }
        }
        const unsigned short* bHp = ldsHi[cur];
        const unsigned short* bLp = ldsLo[cur];
        size_t i0 = ((size_t)((0*4 + par)*8 + icc))*512 + lane*8;
        size_t i1 = ((size_t)((1*4 + par)*8 + icc))*512 + lane*8;
        bf16x8 a0h = *(const bf16x8*)&wHi[i0];
        bf16x8 a0l = *(const bf16x8*)&wLo[i0];
        bf16x8 a1h = *(const bf16x8*)&wHi[i1];
        bf16x8 a1l = *(const bf16x8*)&wLo[i1];
        bf16x8 bh[4], bl[4];
        #pragma unroll
        for (int n=0;n<4;++n){
            int e = eb[n] + offs0;
            bh[n] = *(const bf16x8*)&bHp[e];
            bl[n] = *(const bf16x8*)&bLp[e];
        }
        #pragma unroll
        for (int n=0;n<4;++n){
            acc[0][n] = __builtin_amdgcn_mfma_f32_16x16x32_bf16(a0h, bh[n], acc[0][n], 0,0,0);
            acc[0][n] = __builtin_amdgcn_mfma_f32_16x16x32_bf16(a0h, bl[n], acc[0][n], 0,0,0);
            acc[0][n] = __builtin_amdgcn_mfma_f32_16x16x32_bf16(a0l, bh[n], acc[0][n], 0,0,0);
            acc[1][n] = __builtin_amdgcn_mfma_f32_16x16x32_bf16(a1h, bh[n], acc[1][n], 0,0,0);
            acc[1][n] = __builtin_amdgcn_mfma_f32_16x16x32_bf16(a1h, bl[n], acc[1][n], 0,0,0);
            acc[1][n] = __builtin_amdgcn_mfma_f32_16x16x32_bf16(a1l, bh[n], acc[1][n], 0,0,0);
        }
        if (icc+1 < 8){
            int nb = cur ^ 1;
            *(u16x8*)&ldsHi[nb][sA*8] = rAh; *(u16x8*)&ldsLo[nb][sA*8] = rAl;
            if (hasB){ *(u16x8*)&ldsHi[nb][sB*8] = rBh; *(u16x8*)&ldsLo[nb][sB*8] = rBl; }
        }
        cur ^= 1;
    }
    #pragma unroll
    for (int mm=0;mm<2;++mm){
        int ocb = mm*16 + (lane>>4)*4;
        #pragma unroll
        for (int n=0;n<4;++n){
            int oyr = r0 + wave*2 + (n>>1);
            int oxc = (n&1)*16 + (lane&15);
            int oy = 2*oyr + py, ox = 2*oxc + px;
            float* dst = y1 + ((size_t)tbl*32 + ocb)*4096 + oy*64 + ox;
            #pragma unroll
            for (int j=0;j<4;++j){
                float v = acc[mm][n][j] + Bb[ocb+j];
                dst[(size_t)j*4096] = LRELU(v);
            }
        }
    }
}

// ---------------------------------------------------------------------------
// deconv2: y1 (Ntb,32,64,64) -> out with (t,b) permute, k4 lhs_dil2 pad2, bias.
// ---------------------------------------------------------------------------
__global__ __launch_bounds__(256) void k_deconv2(const float* __restrict__ in,
    const float* __restrict__ W, const float* __restrict__ Bb, float* __restrict__ out,
    int tbOff)
{
    __shared__ float wl[512];
    int tid = threadIdx.x;
    for (int e=tid; e<512; e+=256) wl[e] = W[e];   // [ic][kh][kw], oc=1
    __syncthreads();
    int tbl = blockIdx.y;
    int tb = tbOff + tbl; int t = tb >> 5; int b = tb & 31;
    int idx4 = blockIdx.x*256 + tid;
    int oy = idx4 >> 5; int ox0 = (idx4 & 31)*4;
    int ph = oy & 1;
    const float* base = in + (size_t)tbl*131072;
    float acc0=0.f, acc1=0.f, acc2=0.f, acc3=0.f;
    int ix0 = ox0/2 - 1;
    for (int ic=0; ic<32; ++ic){
        const float* cp = base + ic*4096;
        #pragma unroll
        for (int kk=0; kk<2; ++kk){
            int kh = ph + 2*kk;
            int iy = (oy + kh - 2) >> 1;
            if (iy < 0 || iy > 63) continue;
            const float* rp = cp + (size_t)iy*64;
            float wv0 = (ix0 >= 0)   ? rp[ix0]   : 0.f;
            float wv1 = rp[ix0+1];
            float wv2 = rp[ix0+2];
            float wv3 = (ix0+3 <= 63) ? rp[ix0+3] : 0.f;
            float w0 = wl[ic*16 + kh*4 + 0];
            float w1 = wl[ic*16 + kh*4 + 1];
            float w2 = wl[ic*16 + kh*4 + 2];
            float w3 = wl[ic*16 + kh*4 + 3];
            acc0 += w0*wv0 + w2*wv1;        // p=0: kw 0,2
            acc2 += w0*wv1 + w2*wv2;        // p=2
            acc1 += w1*wv1 + w3*wv2;        // p=1: kw 1,3
            acc3 += w1*wv2 + w3*wv3;        // p=3
        }
    }
    float bv = Bb[0];
    float4 res = make_float4(acc0+bv, acc1+bv, acc2+bv, acc3+bv);
    float* op = out + ((size_t)(b*10 + t))*16384 + (size_t)oy*128 + ox0;
    *(float4*)op = res;
}

// ---------------------------------------------------------------------------
// Workspace (bytes), peak 121,700,352 — layout identical to rounds 5/6.
// ---------------------------------------------------------------------------
extern "C" void kernel_launch(void* const* d_in, const int* in_sizes, int n_in,
                              void* d_out, int out_size, void* d_ws, size_t ws_size,
                              hipStream_t stream)
{
    const float* x    = (const float*)d_in[0];
    const float* ew1  = (const float*)d_in[1];
    const float* eb1  = (const float*)d_in[2];
    const float* ew2  = (const float*)d_in[3];
    const float* eb2  = (const float*)d_in[4];
    const float* ewzr = (const float*)d_in[5];
    const float* ebzr = (const float*)d_in[6];
    const float* ewc  = (const float*)d_in[7];
    const float* ebc  = (const float*)d_in[8];
    const float* dwzr = (const float*)d_in[9];
    const float* dbzr = (const float*)d_in[10];
    const float* dwc  = (const float*)d_in[11];
    const float* dbc  = (const float*)d_in[12];
    const float* dw1  = (const float*)d_in[13];
    const float* db1  = (const float*)d_in[14];
    const float* dw2  = (const float*)d_in[15];
    const float* db2  = (const float*)d_in[16];
    float* out = (float*)d_out;
    char* ws = (char*)d_ws;

    unsigned short* e2hi = (unsigned short*)(ws + 0);
    unsigned short* e2lo = (unsigned short*)(ws + 41943040UL);
    float*          h32  = (float*)(ws + 83886080UL);
    unsigned short* hHi  = (unsigned short*)(ws + 92274688UL);
    unsigned short* hLo  = (unsigned short*)(ws + 96468992UL);
    unsigned short* rhHi = (unsigned short*)(ws + 100663296UL);
    unsigned short* rhLo = (unsigned short*)(ws + 104857600UL);
    float*          z32  = (float*)(ws + 109051904UL);
    unsigned short* A0   = (unsigned short*)(ws + 117440512UL);
    unsigned short* AzrH = A0;            unsigned short* AzrL = A0 + 458752;
    unsigned short* AcH  = A0 + 917504;   unsigned short* AcL  = A0 + 1146880;
    unsigned short* DzrH = A0 + 1376256;  unsigned short* DzrL = A0 + 1605632;
    unsigned short* DcH  = A0 + 1835008;  unsigned short* DcL  = A0 + 1949696;
    unsigned short* D1H  = A0 + 2064384;  unsigned short* D1L  = A0 + 2097152;
    float* e1c = (float*)(ws + 83886080UL);   // phase-1 overlay (40 MB)
    float* y1c = (float*)(ws + 83886080UL);   // phase-4 overlay (33.5 MB)

    // Phase 1: conv1 -> conv2 (e2 split channel-last), chunked x2
    for (int c=0; c<2; ++c){
        int off = c*160;
        k_conv1<<<dim3(16,160),256,0,stream>>>(x + (size_t)off*16384, ew1, eb1, e1c);
        k_conv2<<<dim3(4,160),256,0,stream>>>(e1c, ew2, eb2,
                                              e2hi + (size_t)off*65536,
                                              e2lo + (size_t)off*65536);
    }

    // Weight packing AFTER phase 1 (e1c overlay covers the pack region)
    k_prep<<<224,256,0,stream>>>(ewzr, 128, 0, 128, 57344, AzrH, AzrL);
    k_prep<<<112,256,0,stream>>>(ewc,  128, 0, 128, 28672, AcH,  AcL);
    k_prep<<<112,256,0,stream>>>(dwzr, 128, 64, 64, 28672, DzrH, DzrL);
    k_prep<<< 56,256,0,stream>>>(dwc,  128, 64, 64, 14336, DcH,  DcL);
    k_prep_d1<<<16,256,0,stream>>>(dw1, D1H, D1L);

    hipMemsetAsync(h32, 0, 8388608UL, stream);
    hipMemsetAsync(hHi, 0, 4194304UL, stream);
    hipMemsetAsync(hLo, 0, 4194304UL, stream);

    // Phase 2: encoder GRU scan (2 dispatches per step, fused pointwise)
    for (int t=0; t<10; ++t){
        k_conv5f<0,8,4><<<512,256,0,stream>>>(
            e2hi + (size_t)t*65536, e2lo + (size_t)t*65536, 655360ULL, 8,
            hHi, hLo, 65536ULL, AzrH, AzrL, 16, ebzr,
            h32, nullptr, z32, rhHi, rhLo, nullptr, nullptr, nullptr);
        k_conv5f<1,4,2><<<512,256,0,stream>>>(
            e2hi + (size_t)t*65536, e2lo + (size_t)t*65536, 655360ULL, 8,
            rhHi, rhLo, 65536ULL, AcH, AcL, 16, ebc,
            h32, z32, nullptr, hHi, hLo, h32, nullptr, nullptr);
    }
    // Phase 3: decoder GRU scan; hs (bf16 hi/lo) overlays e2
    for (int t=0; t<10; ++t){
        k_conv5f<0,8,4><<<512,256,0,stream>>>(
            hHi, hLo, 65536ULL, 8,
            hHi, hLo, 65536ULL, DzrH, DzrL, 8, dbzr,
            h32, nullptr, z32, rhHi, rhLo, nullptr, nullptr, nullptr);
        k_conv5f<1,4,2><<<512,256,0,stream>>>(
            rhHi, rhLo, 65536ULL, 8,
            rhHi, rhLo, 65536ULL, DcH, DcL, 8, dbc,
            h32, z32, nullptr, hHi, hLo, h32,
            e2hi + (size_t)t*2097152, e2lo + (size_t)t*2097152);
    }
    // Phase 4: deconv1m (MFMA) -> deconv2, chunked x5 over tb (64 each)
    for (int c=0; c<5; ++c){
        int tbOff = c*64;
        k_deconv1m<<<1024,256,0,stream>>>(
            e2hi + (size_t)tbOff*65536, e2lo + (size_t)tbOff*65536,
            D1H, D1L, db1, y1c);
        k_deconv2<<<dim3(16,64),256,0,stream>>>(y1c, dw2, db2, out, tbOff);
    }
}